// Round 3
// baseline (412.188 us; speedup 1.0000x reference)
//
#include <hip/hip_runtime.h>

#define THREADS 256

// ---------------- degree histogram ----------------
__global__ __launch_bounds__(THREADS) void deg_kernel(const int* __restrict__ dst, int E,
                                                      int* __restrict__ deg) {
    int e = blockIdx.x * blockDim.x + threadIdx.x;
    if (e < E) atomicAdd(&deg[dst[e]], 1);
}

// ---------------- 3-phase exclusive scan over deg (N <= 65536) ----------------
__global__ __launch_bounds__(THREADS) void scan1(const int* __restrict__ deg, int N,
                                                 int* __restrict__ bsum) {
    __shared__ int lds[THREADS];
    int t = threadIdx.x, b = blockIdx.x;
    int i = b * THREADS + t;
    lds[t] = (i < N) ? deg[i] : 0;
    __syncthreads();
    for (int off = THREADS / 2; off > 0; off >>= 1) {
        if (t < off) lds[t] += lds[t + off];
        __syncthreads();
    }
    if (t == 0) bsum[b] = lds[0];
}

__global__ __launch_bounds__(THREADS) void scan2(int* __restrict__ bsum, int nb) {
    __shared__ int lds[THREADS];
    int t = threadIdx.x;
    int v = (t < nb) ? bsum[t] : 0;
    lds[t] = v;
    __syncthreads();
    for (int off = 1; off < THREADS; off <<= 1) {
        int u = (t >= off) ? lds[t - off] : 0;
        __syncthreads();
        lds[t] += u;
        __syncthreads();
    }
    if (t < nb) bsum[t] = lds[t] - v;  // exclusive
}

__global__ __launch_bounds__(THREADS) void scan3(const int* __restrict__ deg, int N,
                                                 const int* __restrict__ bsum,
                                                 int* __restrict__ offs, int* __restrict__ cursor,
                                                 float* __restrict__ dinv) {
    __shared__ int lds[THREADS];
    int t = threadIdx.x, b = blockIdx.x;
    int i = b * THREADS + t;
    int v = (i < N) ? deg[i] : 0;
    lds[t] = v;
    __syncthreads();
    for (int off = 1; off < THREADS; off <<= 1) {
        int u = (t >= off) ? lds[t - off] : 0;
        __syncthreads();
        lds[t] += u;
        __syncthreads();
    }
    if (i < N) {
        int excl = bsum[b] + lds[t] - v;
        offs[i] = excl;
        cursor[i] = excl;
        dinv[i] = rsqrtf((float)v + 1.0f);  // +1 self-loop
    }
}

// ---------------- CSR fill (counting sort of src by dst) ----------------
__global__ __launch_bounds__(THREADS) void fill_kernel(const int* __restrict__ src,
                                                       const int* __restrict__ dst, int E,
                                                       int* __restrict__ cursor,
                                                       int* __restrict__ csr) {
    int e = blockIdx.x * blockDim.x + threadIdx.x;
    if (e < E) {
        int pos = atomicAdd(&cursor[dst[e]], 1);
        csr[pos] = src[e];
    }
}

// ---------------- pull aggregation: wave per node, lane per feature ----------------
__global__ __launch_bounds__(THREADS) void gather_kernel(const float* __restrict__ x,
                                                         const int* __restrict__ offs,
                                                         const int* __restrict__ deg,
                                                         const int* __restrict__ csr,
                                                         const float* __restrict__ dinv,
                                                         float* __restrict__ out, int N) {
    int lane = threadIdx.x & 63;
    int node = (blockIdx.x * blockDim.x + threadIdx.x) >> 6;
    if (node >= N) return;
    float dd = dinv[node];
    float acc = dd * x[(size_t)node * 64 + lane];  // self-loop (final *dd gives dd^2)
    int start = offs[node];
    int end = start + deg[node];
    for (int j0 = start; j0 < end; j0 += 64) {
        int nj = end - j0;
        if (nj > 64) nj = 64;
        int idx = (lane < nj) ? csr[j0 + lane] : 0;
        float wv = (lane < nj) ? dinv[idx] : 0.f;
        for (int jj = 0; jj < nj; ++jj) {
            int s = __shfl(idx, jj);
            float w = __shfl(wv, jj);
            acc += w * x[(size_t)s * 64 + lane];
        }
    }
    out[(size_t)node * 64 + lane] = dd * acc;
}

// ---------------- in-place io = io @ W, W column in REGISTERS, 4-row ILP ----------------
__global__ __launch_bounds__(THREADS) void matmul_stats_kernel(float* __restrict__ io,
                                                               const float* __restrict__ W,
                                                               float* __restrict__ stats, int N) {
    int tid = threadIdx.x;
    int lane = tid & 63;

    // W column `lane` into registers (loop-invariant): w[k] = W[k][lane]
    float w[64];
#pragma unroll
    for (int k = 0; k < 64; ++k) w[k] = W[k * 64 + lane];

    int wave = (blockIdx.x * blockDim.x + tid) >> 6;
    int nwaves = (gridDim.x * blockDim.x) >> 6;
    float sum = 0.f, sq = 0.f;

    for (int i0 = wave * 4; i0 < N; i0 += nwaves * 4) {
        if (i0 + 3 < N) {
            const float4* r0 = (const float4*)(io + (size_t)i0 * 64);
            const float4* r1 = r0 + 16;
            const float4* r2 = r0 + 32;
            const float4* r3 = r0 + 48;
            float a0 = 0.f, a1 = 0.f, a2 = 0.f, a3 = 0.f;
#pragma unroll
            for (int c = 0; c < 16; ++c) {
                float4 va = r0[c], vb = r1[c], vc = r2[c], vd = r3[c];
                float w0 = w[4 * c + 0], w1 = w[4 * c + 1], w2 = w[4 * c + 2], w3 = w[4 * c + 3];
                a0 += va.x * w0 + va.y * w1 + va.z * w2 + va.w * w3;
                a1 += vb.x * w0 + vb.y * w1 + vb.z * w2 + vb.w * w3;
                a2 += vc.x * w0 + vc.y * w1 + vc.z * w2 + vc.w * w3;
                a3 += vd.x * w0 + vd.y * w1 + vd.z * w2 + vd.w * w3;
            }
            io[(size_t)(i0 + 0) * 64 + lane] = a0;
            io[(size_t)(i0 + 1) * 64 + lane] = a1;
            io[(size_t)(i0 + 2) * 64 + lane] = a2;
            io[(size_t)(i0 + 3) * 64 + lane] = a3;
            sum += (a0 + a1) + (a2 + a3);
            sq += a0 * a0 + a1 * a1 + a2 * a2 + a3 * a3;
        } else {
            for (int i = i0; i < N; ++i) {
                const float4* r = (const float4*)(io + (size_t)i * 64);
                float acc = 0.f;
#pragma unroll
                for (int c = 0; c < 16; ++c) {
                    float4 v = r[c];
                    acc += v.x * w[4 * c + 0] + v.y * w[4 * c + 1] + v.z * w[4 * c + 2] +
                           v.w * w[4 * c + 3];
                }
                io[(size_t)i * 64 + lane] = acc;
                sum += acc;
                sq += acc * acc;
            }
        }
    }
    atomicAdd(&stats[lane], sum);
    atomicAdd(&stats[64 + lane], sq);
}

// ---------------- BN + ReLU in place ----------------
__global__ __launch_bounds__(THREADS) void bn_relu_kernel(float* __restrict__ io,
                                                          const float* __restrict__ stats,
                                                          const float* __restrict__ gamma,
                                                          const float* __restrict__ beta,
                                                          int n4, float invN) {
    int t = blockIdx.x * blockDim.x + threadIdx.x;
    if (t >= n4) return;
    int f0 = (t & 15) * 4;
    float4 v = ((const float4*)io)[t];
    float vv[4] = {v.x, v.y, v.z, v.w};
    float o[4];
#pragma unroll
    for (int j = 0; j < 4; ++j) {
        int f = f0 + j;
        float mean = stats[f] * invN;
        float var = stats[64 + f] * invN - mean * mean;
        float scale = gamma[f] * rsqrtf(var + 1e-5f);
        float shift = beta[f] - mean * scale;
        float y = vv[j] * scale + shift;
        o[j] = y > 0.f ? y : 0.f;
    }
    float4 r = {o[0], o[1], o[2], o[3]};
    ((float4*)io)[t] = r;
}

// ---------------- fallback (push path) kernels ----------------
__global__ __launch_bounds__(THREADS) void dinv_kernel(const int* __restrict__ deg,
                                                       float* __restrict__ dinv, int N) {
    int i = blockIdx.x * blockDim.x + threadIdx.x;
    if (i < N) dinv[i] = rsqrtf((float)deg[i] + 1.0f);
}

__global__ __launch_bounds__(THREADS) void selfloop_kernel(const float4* __restrict__ x4,
                                                           const float* __restrict__ dinv,
                                                           float4* __restrict__ out4, int n4) {
    int t = blockIdx.x * blockDim.x + threadIdx.x;
    if (t >= n4) return;
    int node = t >> 4;
    float s = dinv[node];
    s *= s;
    float4 v = x4[t];
    v.x *= s; v.y *= s; v.z *= s; v.w *= s;
    out4[t] = v;
}

__global__ __launch_bounds__(THREADS) void scatter_kernel(const int* __restrict__ src,
                                                          const int* __restrict__ dst, int E,
                                                          const float* __restrict__ x,
                                                          const float* __restrict__ dinv,
                                                          float* __restrict__ out) {
    int lane = threadIdx.x & 63;
    int wave = (blockIdx.x * blockDim.x + threadIdx.x) >> 6;
    int nwaves = (gridDim.x * blockDim.x) >> 6;
    for (int e = wave; e < E; e += nwaves) {
        int s = src[e];
        int d = dst[e];
        float nrm = dinv[s] * dinv[d];
        atomicAdd(&out[d * 64 + lane], x[s * 64 + lane] * nrm);
    }
}

extern "C" void kernel_launch(void* const* d_in, const int* in_sizes, int n_in,
                              void* d_out, int out_size, void* d_ws, size_t ws_size,
                              hipStream_t stream) {
    const float* x     = (const float*)d_in[0];
    const int*   edges = (const int*)d_in[1];
    const float* W     = (const float*)d_in[2];
    // d_in[3] = b cancels exactly in training-mode BN
    const float* gamma = (const float*)d_in[4];
    const float* beta  = (const float*)d_in[5];
    float* out = (float*)d_out;

    const int N = in_sizes[0] / 64;
    const int E = in_sizes[1] / 2;
    const int* src = edges;
    const int* dst = edges + E;
    const int n4 = N * 16;
    const int nb = (N + THREADS - 1) / THREADS;

    char* ws = (char*)d_ws;
    size_t need = (size_t)16 * N + 512 + (size_t)4 * E + 4 * THREADS;

    if (ws_size >= need && nb <= THREADS) {
        // layout: deg[N] | offs[N] | cursor[N] | dinv[N] | stats[128] | bsum[256] | csr[E]
        int*   deg    = (int*)ws;
        int*   offs   = deg + N;
        int*   cursor = offs + N;
        float* dinv   = (float*)(cursor + N);
        float* stats  = dinv + N;
        int*   bsum   = (int*)(stats + 128);
        int*   csr    = bsum + THREADS;

        hipMemsetAsync(deg, 0, (size_t)4 * N, stream);
        hipMemsetAsync(stats, 0, 512, stream);

        deg_kernel<<<(E + THREADS - 1) / THREADS, THREADS, 0, stream>>>(dst, E, deg);
        scan1<<<nb, THREADS, 0, stream>>>(deg, N, bsum);
        scan2<<<1, THREADS, 0, stream>>>(bsum, nb);
        scan3<<<nb, THREADS, 0, stream>>>(deg, N, bsum, offs, cursor, dinv);
        fill_kernel<<<(E + THREADS - 1) / THREADS, THREADS, 0, stream>>>(src, dst, E, cursor, csr);
        gather_kernel<<<(N * 64 + THREADS - 1) / THREADS, THREADS, 0, stream>>>(
            x, offs, deg, csr, dinv, out, N);
        matmul_stats_kernel<<<2048, THREADS, 0, stream>>>(out, W, stats, N);
        bn_relu_kernel<<<(n4 + THREADS - 1) / THREADS, THREADS, 0, stream>>>(
            out, stats, gamma, beta, n4, 1.0f / (float)N);
    } else {
        // fallback: push path (ws: deg[N] | stats[128] | dinv[N])
        int*   deg   = (int*)ws;
        float* stats = (float*)(ws + (size_t)N * 4);
        float* dinv  = (float*)(ws + (size_t)N * 4 + 512);

        hipMemsetAsync(ws, 0, (size_t)N * 4 + 512, stream);
        deg_kernel<<<(E + THREADS - 1) / THREADS, THREADS, 0, stream>>>(dst, E, deg);
        dinv_kernel<<<(N + THREADS - 1) / THREADS, THREADS, 0, stream>>>(deg, dinv, N);
        selfloop_kernel<<<(n4 + THREADS - 1) / THREADS, THREADS, 0, stream>>>(
            (const float4*)x, dinv, (float4*)out, n4);
        scatter_kernel<<<1024, THREADS, 0, stream>>>(src, dst, E, x, dinv, out);
        matmul_stats_kernel<<<512, THREADS, 0, stream>>>(out, W, stats, N);
        bn_relu_kernel<<<(n4 + THREADS - 1) / THREADS, THREADS, 0, stream>>>(
            out, stats, gamma, beta, n4, 1.0f / (float)N);
    }
}

// Round 4
// 333.241 us; speedup vs baseline: 1.2369x; 1.2369x over previous
//
#include <hip/hip_runtime.h>

#define THREADS 256

// ---------------- degree histogram ----------------
__global__ __launch_bounds__(THREADS) void deg_kernel(const int* __restrict__ dst, int E,
                                                      int* __restrict__ deg) {
    int e = blockIdx.x * blockDim.x + threadIdx.x;
    if (e < E) atomicAdd(&deg[dst[e]], 1);
}

// ---------------- 3-phase exclusive scan over deg (N <= 65536) ----------------
__global__ __launch_bounds__(THREADS) void scan1(const int* __restrict__ deg, int N,
                                                 int* __restrict__ bsum) {
    __shared__ int lds[THREADS];
    int t = threadIdx.x, b = blockIdx.x;
    int i = b * THREADS + t;
    lds[t] = (i < N) ? deg[i] : 0;
    __syncthreads();
    for (int off = THREADS / 2; off > 0; off >>= 1) {
        if (t < off) lds[t] += lds[t + off];
        __syncthreads();
    }
    if (t == 0) bsum[b] = lds[0];
}

__global__ __launch_bounds__(THREADS) void scan2(int* __restrict__ bsum, int nb) {
    __shared__ int lds[THREADS];
    int t = threadIdx.x;
    int v = (t < nb) ? bsum[t] : 0;
    lds[t] = v;
    __syncthreads();
    for (int off = 1; off < THREADS; off <<= 1) {
        int u = (t >= off) ? lds[t - off] : 0;
        __syncthreads();
        lds[t] += u;
        __syncthreads();
    }
    if (t < nb) bsum[t] = lds[t] - v;  // exclusive
}

__global__ __launch_bounds__(THREADS) void scan3(const int* __restrict__ deg, int N,
                                                 const int* __restrict__ bsum,
                                                 int* __restrict__ offs, int* __restrict__ cursor,
                                                 float* __restrict__ dinv) {
    __shared__ int lds[THREADS];
    int t = threadIdx.x, b = blockIdx.x;
    int i = b * THREADS + t;
    int v = (i < N) ? deg[i] : 0;
    lds[t] = v;
    __syncthreads();
    for (int off = 1; off < THREADS; off <<= 1) {
        int u = (t >= off) ? lds[t - off] : 0;
        __syncthreads();
        lds[t] += u;
        __syncthreads();
    }
    if (i < N) {
        int excl = bsum[b] + lds[t] - v;
        offs[i] = excl;
        cursor[i] = excl;
        dinv[i] = rsqrtf((float)v + 1.0f);  // +1 self-loop
    }
}

// ---------------- CSR fill (counting sort of src by dst) ----------------
__global__ __launch_bounds__(THREADS) void fill_kernel(const int* __restrict__ src,
                                                       const int* __restrict__ dst, int E,
                                                       int* __restrict__ cursor,
                                                       int* __restrict__ csr) {
    int e = blockIdx.x * blockDim.x + threadIdx.x;
    if (e < E) {
        int pos = atomicAdd(&cursor[dst[e]], 1);
        csr[pos] = src[e];
    }
}

// ---------------- pull aggregation: wave per node, lane per feature ----------------
// node is wave-uniform (readfirstlane) -> offs/deg/csr/dinv accesses become
// scalar(SGPR) loads; per edge only one coalesced 256B vector load + FMA.
__global__ __launch_bounds__(THREADS) void gather_kernel(const float* __restrict__ x,
                                                         const int* __restrict__ offs,
                                                         const int* __restrict__ deg,
                                                         const int* __restrict__ csr,
                                                         const float* __restrict__ dinv,
                                                         float* __restrict__ out, int N) {
    int lane = threadIdx.x & 63;
    int node = __builtin_amdgcn_readfirstlane(
        (int)((blockIdx.x * blockDim.x + threadIdx.x) >> 6));
    if (node >= N) return;
    float dd = dinv[node];
    float acc = dd * x[((size_t)node << 6) + lane];  // self-loop (final *dd -> dd^2)
    int start = offs[node];
    int cnt = deg[node];
    const int* __restrict__ row = csr + start;
    int j = 0;
    for (; j + 4 <= cnt; j += 4) {
        int s0 = __builtin_amdgcn_readfirstlane(row[j + 0]);
        int s1 = __builtin_amdgcn_readfirstlane(row[j + 1]);
        int s2 = __builtin_amdgcn_readfirstlane(row[j + 2]);
        int s3 = __builtin_amdgcn_readfirstlane(row[j + 3]);
        float w0 = dinv[s0], w1 = dinv[s1], w2 = dinv[s2], w3 = dinv[s3];
        float v0 = x[((size_t)s0 << 6) + lane];
        float v1 = x[((size_t)s1 << 6) + lane];
        float v2 = x[((size_t)s2 << 6) + lane];
        float v3 = x[((size_t)s3 << 6) + lane];
        acc += w0 * v0 + w1 * v1 + w2 * v2 + w3 * v3;
    }
    for (; j < cnt; ++j) {
        int s = __builtin_amdgcn_readfirstlane(row[j]);
        acc += dinv[s] * x[((size_t)s << 6) + lane];
    }
    out[((size_t)node << 6) + lane] = dd * acc;
}

// ---------------- LDS-tiled in-place matmul io = io @ W, fused stats ----------------
// block = 256 threads, 64-row tile; thread computes 4 rows x 4 cols.
#define AT_LD 68  // padded leading dim (floats): dr=4 -> bank offset 16; 16B-aligned
__global__ __launch_bounds__(THREADS) void matmul_stats_kernel(float* __restrict__ io,
                                                               const float* __restrict__ W,
                                                               float* __restrict__ stats, int N) {
    __shared__ float Wl[64 * 64];    // Wl[k*64+c]
    __shared__ float At[64 * AT_LD]; // At[r*AT_LD+k]
    __shared__ float bred[128];
    int tid = threadIdx.x;

    for (int i = tid; i < 1024; i += THREADS)
        ((float4*)Wl)[i] = ((const float4*)W)[i];

    int c0 = (tid & 15) * 4;
    int r0 = (tid >> 4) * 4;
    int ntiles = (N + 63) >> 6;
    float sums[4] = {0.f, 0.f, 0.f, 0.f};
    float sqs[4] = {0.f, 0.f, 0.f, 0.f};

    for (int tile = blockIdx.x; tile < ntiles; tile += gridDim.x) {
        int base = tile << 6;
        __syncthreads();  // protect At (prev iter reads / Wl stage on first)
        for (int g = tid; g < 1024; g += THREADS) {
            int r = g >> 4, cc = (g & 15) << 2;
            int rowi = base + r;
            float4 v = {0.f, 0.f, 0.f, 0.f};
            if (rowi < N) v = *(const float4*)(io + ((size_t)rowi << 6) + cc);
            *(float4*)(&At[r * AT_LD + cc]) = v;
        }
        __syncthreads();

        float acc[4][4] = {};
#pragma unroll
        for (int k0 = 0; k0 < 64; k0 += 4) {
            float4 a[4], wf[4];
#pragma unroll
            for (int i = 0; i < 4; ++i)
                a[i] = *(const float4*)(&At[(r0 + i) * AT_LD + k0]);
#pragma unroll
            for (int q = 0; q < 4; ++q)
                wf[q] = *(const float4*)(&Wl[(k0 + q) * 64 + c0]);
#pragma unroll
            for (int i = 0; i < 4; ++i) {
                const float* ap = (const float*)&a[i];
#pragma unroll
                for (int j = 0; j < 4; ++j) {
                    acc[i][j] += ap[0] * ((const float*)&wf[0])[j] +
                                 ap[1] * ((const float*)&wf[1])[j] +
                                 ap[2] * ((const float*)&wf[2])[j] +
                                 ap[3] * ((const float*)&wf[3])[j];
                }
            }
        }

#pragma unroll
        for (int i = 0; i < 4; ++i) {
            int rowi = base + r0 + i;
            if (rowi < N) {
                float4 o = {acc[i][0], acc[i][1], acc[i][2], acc[i][3]};
                *(float4*)(io + ((size_t)rowi << 6) + c0) = o;
#pragma unroll
                for (int j = 0; j < 4; ++j) {
                    sums[j] += acc[i][j];
                    sqs[j] += acc[i][j] * acc[i][j];
                }
            }
        }
    }

    // block-level stats reduction, then one atomic per feature per block
    __syncthreads();
    if (tid < 128) bred[tid] = 0.f;
    __syncthreads();
#pragma unroll
    for (int j = 0; j < 4; ++j) {
        atomicAdd(&bred[c0 + j], sums[j]);
        atomicAdd(&bred[64 + c0 + j], sqs[j]);
    }
    __syncthreads();
    if (tid < 128) atomicAdd(&stats[tid], bred[tid]);
}

// ---------------- BN + ReLU in place ----------------
__global__ __launch_bounds__(THREADS) void bn_relu_kernel(float* __restrict__ io,
                                                          const float* __restrict__ stats,
                                                          const float* __restrict__ gamma,
                                                          const float* __restrict__ beta,
                                                          int n4, float invN) {
    int t = blockIdx.x * blockDim.x + threadIdx.x;
    if (t >= n4) return;
    int f0 = (t & 15) * 4;
    float4 v = ((const float4*)io)[t];
    float vv[4] = {v.x, v.y, v.z, v.w};
    float o[4];
#pragma unroll
    for (int j = 0; j < 4; ++j) {
        int f = f0 + j;
        float mean = stats[f] * invN;
        float var = stats[64 + f] * invN - mean * mean;
        float scale = gamma[f] * rsqrtf(var + 1e-5f);
        float shift = beta[f] - mean * scale;
        float y = vv[j] * scale + shift;
        o[j] = y > 0.f ? y : 0.f;
    }
    float4 r = {o[0], o[1], o[2], o[3]};
    ((float4*)io)[t] = r;
}

// ---------------- fallback (push path) kernels ----------------
__global__ __launch_bounds__(THREADS) void dinv_kernel(const int* __restrict__ deg,
                                                       float* __restrict__ dinv, int N) {
    int i = blockIdx.x * blockDim.x + threadIdx.x;
    if (i < N) dinv[i] = rsqrtf((float)deg[i] + 1.0f);
}

__global__ __launch_bounds__(THREADS) void selfloop_kernel(const float4* __restrict__ x4,
                                                           const float* __restrict__ dinv,
                                                           float4* __restrict__ out4, int n4) {
    int t = blockIdx.x * blockDim.x + threadIdx.x;
    if (t >= n4) return;
    int node = t >> 4;
    float s = dinv[node];
    s *= s;
    float4 v = x4[t];
    v.x *= s; v.y *= s; v.z *= s; v.w *= s;
    out4[t] = v;
}

__global__ __launch_bounds__(THREADS) void scatter_kernel(const int* __restrict__ src,
                                                          const int* __restrict__ dst, int E,
                                                          const float* __restrict__ x,
                                                          const float* __restrict__ dinv,
                                                          float* __restrict__ out) {
    int lane = threadIdx.x & 63;
    int wave = (blockIdx.x * blockDim.x + threadIdx.x) >> 6;
    int nwaves = (gridDim.x * blockDim.x) >> 6;
    for (int e = wave; e < E; e += nwaves) {
        int s = src[e];
        int d = dst[e];
        float nrm = dinv[s] * dinv[d];
        atomicAdd(&out[d * 64 + lane], x[s * 64 + lane] * nrm);
    }
}

extern "C" void kernel_launch(void* const* d_in, const int* in_sizes, int n_in,
                              void* d_out, int out_size, void* d_ws, size_t ws_size,
                              hipStream_t stream) {
    const float* x     = (const float*)d_in[0];
    const int*   edges = (const int*)d_in[1];
    const float* W     = (const float*)d_in[2];
    // d_in[3] = b cancels exactly in training-mode BN
    const float* gamma = (const float*)d_in[4];
    const float* beta  = (const float*)d_in[5];
    float* out = (float*)d_out;

    const int N = in_sizes[0] / 64;
    const int E = in_sizes[1] / 2;
    const int* src = edges;
    const int* dst = edges + E;
    const int n4 = N * 16;
    const int nb = (N + THREADS - 1) / THREADS;

    char* ws = (char*)d_ws;
    size_t need = (size_t)16 * N + 512 + (size_t)4 * E + 4 * THREADS;

    if (ws_size >= need && nb <= THREADS) {
        // layout: deg[N] | offs[N] | cursor[N] | dinv[N] | stats[128] | bsum[256] | csr[E]
        int*   deg    = (int*)ws;
        int*   offs   = deg + N;
        int*   cursor = offs + N;
        float* dinv   = (float*)(cursor + N);
        float* stats  = dinv + N;
        int*   bsum   = (int*)(stats + 128);
        int*   csr    = bsum + THREADS;

        hipMemsetAsync(deg, 0, (size_t)4 * N, stream);
        hipMemsetAsync(stats, 0, 512, stream);

        deg_kernel<<<(E + THREADS - 1) / THREADS, THREADS, 0, stream>>>(dst, E, deg);
        scan1<<<nb, THREADS, 0, stream>>>(deg, N, bsum);
        scan2<<<1, THREADS, 0, stream>>>(bsum, nb);
        scan3<<<nb, THREADS, 0, stream>>>(deg, N, bsum, offs, cursor, dinv);
        fill_kernel<<<(E + THREADS - 1) / THREADS, THREADS, 0, stream>>>(src, dst, E, cursor, csr);
        gather_kernel<<<(N * 64 + THREADS - 1) / THREADS, THREADS, 0, stream>>>(
            x, offs, deg, csr, dinv, out, N);
        matmul_stats_kernel<<<512, THREADS, 0, stream>>>(out, W, stats, N);
        bn_relu_kernel<<<(n4 + THREADS - 1) / THREADS, THREADS, 0, stream>>>(
            out, stats, gamma, beta, n4, 1.0f / (float)N);
    } else {
        // fallback: push path (ws: deg[N] | stats[128] | dinv[N])
        int*   deg   = (int*)ws;
        float* stats = (float*)(ws + (size_t)N * 4);
        float* dinv  = (float*)(ws + (size_t)N * 4 + 512);

        hipMemsetAsync(ws, 0, (size_t)N * 4 + 512, stream);
        deg_kernel<<<(E + THREADS - 1) / THREADS, THREADS, 0, stream>>>(dst, E, deg);
        dinv_kernel<<<(N + THREADS - 1) / THREADS, THREADS, 0, stream>>>(deg, dinv, N);
        selfloop_kernel<<<(n4 + THREADS - 1) / THREADS, THREADS, 0, stream>>>(
            (const float4*)x, dinv, (float4*)out, n4);
        scatter_kernel<<<1024, THREADS, 0, stream>>>(src, dst, E, x, dinv, out);
        matmul_stats_kernel<<<512, THREADS, 0, stream>>>(out, W, stats, N);
        bn_relu_kernel<<<(n4 + THREADS - 1) / THREADS, THREADS, 0, stream>>>(
            out, stats, gamma, beta, n4, 1.0f / (float)N);
    }
}

// Round 5
// 219.678 us; speedup vs baseline: 1.8763x; 1.5170x over previous
//
#include <hip/hip_runtime.h>

#define THREADS 256

// ---------------- degree histogram ----------------
__global__ __launch_bounds__(THREADS) void deg_kernel(const int* __restrict__ dst, int E,
                                                      int* __restrict__ deg) {
    int e = blockIdx.x * blockDim.x + threadIdx.x;
    if (e < E) atomicAdd(&deg[dst[e]], 1);
}

// ---------------- 3-phase exclusive scan over deg (N <= 65536) ----------------
__global__ __launch_bounds__(THREADS) void scan1(const int* __restrict__ deg, int N,
                                                 int* __restrict__ bsum) {
    __shared__ int lds[THREADS];
    int t = threadIdx.x, b = blockIdx.x;
    int i = b * THREADS + t;
    lds[t] = (i < N) ? deg[i] : 0;
    __syncthreads();
    for (int off = THREADS / 2; off > 0; off >>= 1) {
        if (t < off) lds[t] += lds[t + off];
        __syncthreads();
    }
    if (t == 0) bsum[b] = lds[0];
}

__global__ __launch_bounds__(THREADS) void scan2(int* __restrict__ bsum, int nb) {
    __shared__ int lds[THREADS];
    int t = threadIdx.x;
    int v = (t < nb) ? bsum[t] : 0;
    lds[t] = v;
    __syncthreads();
    for (int off = 1; off < THREADS; off <<= 1) {
        int u = (t >= off) ? lds[t - off] : 0;
        __syncthreads();
        lds[t] += u;
        __syncthreads();
    }
    if (t < nb) bsum[t] = lds[t] - v;  // exclusive
}

__global__ __launch_bounds__(THREADS) void scan3(const int* __restrict__ deg, int N,
                                                 const int* __restrict__ bsum,
                                                 int* __restrict__ offs, int* __restrict__ cursor,
                                                 float* __restrict__ dinv) {
    __shared__ int lds[THREADS];
    int t = threadIdx.x, b = blockIdx.x;
    int i = b * THREADS + t;
    int v = (i < N) ? deg[i] : 0;
    lds[t] = v;
    __syncthreads();
    for (int off = 1; off < THREADS; off <<= 1) {
        int u = (t >= off) ? lds[t - off] : 0;
        __syncthreads();
        lds[t] += u;
        __syncthreads();
    }
    if (i < N) {
        int excl = bsum[b] + lds[t] - v;
        offs[i] = excl;
        cursor[i] = excl;
        dinv[i] = rsqrtf((float)v + 1.0f);  // +1 self-loop
    }
}

// ---------------- CSR fill (counting sort of src by dst) ----------------
__global__ __launch_bounds__(THREADS) void fill_kernel(const int* __restrict__ src,
                                                       const int* __restrict__ dst, int E,
                                                       int* __restrict__ cursor,
                                                       int* __restrict__ csr) {
    int e = blockIdx.x * blockDim.x + threadIdx.x;
    if (e < E) {
        int pos = atomicAdd(&cursor[dst[e]], 1);
        csr[pos] = src[e];
    }
}

// ---------------- pull aggregation: wave per node, lane per feature ----------------
// node wave-uniform -> offs/deg/csr/dinv accesses are scalar(SGPR) loads;
// per edge one coalesced 256B vector load + FMA.
__global__ __launch_bounds__(THREADS) void gather_kernel(const float* __restrict__ x,
                                                         const int* __restrict__ offs,
                                                         const int* __restrict__ deg,
                                                         const int* __restrict__ csr,
                                                         const float* __restrict__ dinv,
                                                         float* __restrict__ out, int N) {
    int lane = threadIdx.x & 63;
    int node = __builtin_amdgcn_readfirstlane(
        (int)((blockIdx.x * blockDim.x + threadIdx.x) >> 6));
    if (node >= N) return;
    float dd = dinv[node];
    float acc = dd * x[((size_t)node << 6) + lane];  // self-loop (final *dd -> dd^2)
    int start = offs[node];
    int cnt = deg[node];
    const int* __restrict__ row = csr + start;
    int j = 0;
    for (; j + 4 <= cnt; j += 4) {
        int s0 = __builtin_amdgcn_readfirstlane(row[j + 0]);
        int s1 = __builtin_amdgcn_readfirstlane(row[j + 1]);
        int s2 = __builtin_amdgcn_readfirstlane(row[j + 2]);
        int s3 = __builtin_amdgcn_readfirstlane(row[j + 3]);
        float w0 = dinv[s0], w1 = dinv[s1], w2 = dinv[s2], w3 = dinv[s3];
        float v0 = x[((size_t)s0 << 6) + lane];
        float v1 = x[((size_t)s1 << 6) + lane];
        float v2 = x[((size_t)s2 << 6) + lane];
        float v3 = x[((size_t)s3 << 6) + lane];
        acc += w0 * v0 + w1 * v1 + w2 * v2 + w3 * v3;
    }
    for (; j < cnt; ++j) {
        int s = __builtin_amdgcn_readfirstlane(row[j]);
        acc += dinv[s] * x[((size_t)s << 6) + lane];
    }
    out[((size_t)node << 6) + lane] = dd * acc;
}

// ---------------- LDS-tiled in-place matmul io = io @ W, fused stats ----------------
// block = 256 threads, 64-row tile; thread computes 4 rows x 4 cols.
// k-loop kept rolled (#pragma unroll 1): 8 independent ds_read_b128 + 64 FMAs
// per iteration is enough ILP; full unroll spilled (VGPR=256, 200MB scratch, R4).
#define AT_LD 68  // padded leading dim (floats): 16B-aligned, breaks pow2 stride
__global__ __launch_bounds__(THREADS) void matmul_stats_kernel(float* __restrict__ io,
                                                               const float* __restrict__ W,
                                                               float* __restrict__ stats, int N) {
    __shared__ float Wl[64 * 64];    // Wl[k*64+c]
    __shared__ float At[64 * AT_LD]; // At[r*AT_LD+k]
    __shared__ float bred[128];
    int tid = threadIdx.x;

    for (int i = tid; i < 1024; i += THREADS)
        ((float4*)Wl)[i] = ((const float4*)W)[i];

    int c0 = (tid & 15) * 4;
    int r0 = (tid >> 4) * 4;
    int ntiles = (N + 63) >> 6;
    float sums[4] = {0.f, 0.f, 0.f, 0.f};
    float sqs[4] = {0.f, 0.f, 0.f, 0.f};

    for (int tile = blockIdx.x; tile < ntiles; tile += gridDim.x) {
        int base = tile << 6;
        __syncthreads();  // Wl ready (1st iter); At reads of prev iter done
        for (int g = tid; g < 1024; g += THREADS) {
            int r = g >> 4, cc = (g & 15) << 2;
            int rowi = base + r;
            float4 v = {0.f, 0.f, 0.f, 0.f};
            if (rowi < N) v = *(const float4*)(io + ((size_t)rowi << 6) + cc);
            *(float4*)(&At[r * AT_LD + cc]) = v;
        }
        __syncthreads();

        float acc[4][4] = {};
#pragma unroll 1
        for (int k0 = 0; k0 < 64; k0 += 4) {
            float4 a[4], wf[4];
#pragma unroll
            for (int i = 0; i < 4; ++i)
                a[i] = *(const float4*)(&At[(r0 + i) * AT_LD + k0]);
#pragma unroll
            for (int q = 0; q < 4; ++q)
                wf[q] = *(const float4*)(&Wl[(k0 + q) * 64 + c0]);
#pragma unroll
            for (int i = 0; i < 4; ++i) {
                const float* ap = (const float*)&a[i];
#pragma unroll
                for (int j = 0; j < 4; ++j) {
                    acc[i][j] += ap[0] * ((const float*)&wf[0])[j] +
                                 ap[1] * ((const float*)&wf[1])[j] +
                                 ap[2] * ((const float*)&wf[2])[j] +
                                 ap[3] * ((const float*)&wf[3])[j];
                }
            }
        }

#pragma unroll
        for (int i = 0; i < 4; ++i) {
            int rowi = base + r0 + i;
            if (rowi < N) {
                float4 o = {acc[i][0], acc[i][1], acc[i][2], acc[i][3]};
                *(float4*)(io + ((size_t)rowi << 6) + c0) = o;
#pragma unroll
                for (int j = 0; j < 4; ++j) {
                    sums[j] += acc[i][j];
                    sqs[j] += acc[i][j] * acc[i][j];
                }
            }
        }
    }

    // block-level stats reduction, then one atomic per feature per block
    __syncthreads();
    if (tid < 128) bred[tid] = 0.f;
    __syncthreads();
#pragma unroll
    for (int j = 0; j < 4; ++j) {
        atomicAdd(&bred[c0 + j], sums[j]);
        atomicAdd(&bred[64 + c0 + j], sqs[j]);
    }
    __syncthreads();
    if (tid < 128) atomicAdd(&stats[tid], bred[tid]);
}

// ---------------- BN + ReLU in place ----------------
__global__ __launch_bounds__(THREADS) void bn_relu_kernel(float* __restrict__ io,
                                                          const float* __restrict__ stats,
                                                          const float* __restrict__ gamma,
                                                          const float* __restrict__ beta,
                                                          int n4, float invN) {
    int t = blockIdx.x * blockDim.x + threadIdx.x;
    if (t >= n4) return;
    int f0 = (t & 15) * 4;
    float4 v = ((const float4*)io)[t];
    float vv[4] = {v.x, v.y, v.z, v.w};
    float o[4];
#pragma unroll
    for (int j = 0; j < 4; ++j) {
        int f = f0 + j;
        float mean = stats[f] * invN;
        float var = stats[64 + f] * invN - mean * mean;
        float scale = gamma[f] * rsqrtf(var + 1e-5f);
        float shift = beta[f] - mean * scale;
        float y = vv[j] * scale + shift;
        o[j] = y > 0.f ? y : 0.f;
    }
    float4 r = {o[0], o[1], o[2], o[3]};
    ((float4*)io)[t] = r;
}

// ---------------- fallback (push path) kernels ----------------
__global__ __launch_bounds__(THREADS) void dinv_kernel(const int* __restrict__ deg,
                                                       float* __restrict__ dinv, int N) {
    int i = blockIdx.x * blockDim.x + threadIdx.x;
    if (i < N) dinv[i] = rsqrtf((float)deg[i] + 1.0f);
}

__global__ __launch_bounds__(THREADS) void selfloop_kernel(const float4* __restrict__ x4,
                                                           const float* __restrict__ dinv,
                                                           float4* __restrict__ out4, int n4) {
    int t = blockIdx.x * blockDim.x + threadIdx.x;
    if (t >= n4) return;
    int node = t >> 4;
    float s = dinv[node];
    s *= s;
    float4 v = x4[t];
    v.x *= s; v.y *= s; v.z *= s; v.w *= s;
    out4[t] = v;
}

__global__ __launch_bounds__(THREADS) void scatter_kernel(const int* __restrict__ src,
                                                          const int* __restrict__ dst, int E,
                                                          const float* __restrict__ x,
                                                          const float* __restrict__ dinv,
                                                          float* __restrict__ out) {
    int lane = threadIdx.x & 63;
    int wave = (blockIdx.x * blockDim.x + threadIdx.x) >> 6;
    int nwaves = (gridDim.x * blockDim.x) >> 6;
    for (int e = wave; e < E; e += nwaves) {
        int s = src[e];
        int d = dst[e];
        float nrm = dinv[s] * dinv[d];
        atomicAdd(&out[d * 64 + lane], x[s * 64 + lane] * nrm);
    }
}

extern "C" void kernel_launch(void* const* d_in, const int* in_sizes, int n_in,
                              void* d_out, int out_size, void* d_ws, size_t ws_size,
                              hipStream_t stream) {
    const float* x     = (const float*)d_in[0];
    const int*   edges = (const int*)d_in[1];
    const float* W     = (const float*)d_in[2];
    // d_in[3] = b cancels exactly in training-mode BN
    const float* gamma = (const float*)d_in[4];
    const float* beta  = (const float*)d_in[5];
    float* out = (float*)d_out;

    const int N = in_sizes[0] / 64;
    const int E = in_sizes[1] / 2;
    const int* src = edges;
    const int* dst = edges + E;
    const int n4 = N * 16;
    const int nb = (N + THREADS - 1) / THREADS;

    char* ws = (char*)d_ws;
    size_t need = (size_t)16 * N + 512 + (size_t)4 * E + 4 * THREADS;

    if (ws_size >= need && nb <= THREADS) {
        // layout: deg[N] | offs[N] | cursor[N] | dinv[N] | stats[128] | bsum[256] | csr[E]
        int*   deg    = (int*)ws;
        int*   offs   = deg + N;
        int*   cursor = offs + N;
        float* dinv   = (float*)(cursor + N);
        float* stats  = dinv + N;
        int*   bsum   = (int*)(stats + 128);
        int*   csr    = bsum + THREADS;

        hipMemsetAsync(deg, 0, (size_t)4 * N, stream);
        hipMemsetAsync(stats, 0, 512, stream);

        deg_kernel<<<(E + THREADS - 1) / THREADS, THREADS, 0, stream>>>(dst, E, deg);
        scan1<<<nb, THREADS, 0, stream>>>(deg, N, bsum);
        scan2<<<1, THREADS, 0, stream>>>(bsum, nb);
        scan3<<<nb, THREADS, 0, stream>>>(deg, N, bsum, offs, cursor, dinv);
        fill_kernel<<<(E + THREADS - 1) / THREADS, THREADS, 0, stream>>>(src, dst, E, cursor, csr);
        gather_kernel<<<(N * 64 + THREADS - 1) / THREADS, THREADS, 0, stream>>>(
            x, offs, deg, csr, dinv, out, N);
        int ntiles = (N + 63) >> 6;
        matmul_stats_kernel<<<(ntiles < 1024 ? ntiles : 1024), THREADS, 0, stream>>>(
            out, W, stats, N);
        bn_relu_kernel<<<(n4 + THREADS - 1) / THREADS, THREADS, 0, stream>>>(
            out, stats, gamma, beta, n4, 1.0f / (float)N);
    } else {
        // fallback: push path (ws: deg[N] | stats[128] | dinv[N])
        int*   deg   = (int*)ws;
        float* stats = (float*)(ws + (size_t)N * 4);
        float* dinv  = (float*)(ws + (size_t)N * 4 + 512);

        hipMemsetAsync(ws, 0, (size_t)N * 4 + 512, stream);
        deg_kernel<<<(E + THREADS - 1) / THREADS, THREADS, 0, stream>>>(dst, E, deg);
        dinv_kernel<<<(N + THREADS - 1) / THREADS, THREADS, 0, stream>>>(deg, dinv, N);
        selfloop_kernel<<<(n4 + THREADS - 1) / THREADS, THREADS, 0, stream>>>(
            (const float4*)x, dinv, (float4*)out, n4);
        scatter_kernel<<<1024, THREADS, 0, stream>>>(src, dst, E, x, dinv, out);
        matmul_stats_kernel<<<512, THREADS, 0, stream>>>(out, W, stats, N);
        bn_relu_kernel<<<(n4 + THREADS - 1) / THREADS, THREADS, 0, stream>>>(
            out, stats, gamma, beta, n4, 1.0f / (float)N);
    }
}

// Round 6
// 195.813 us; speedup vs baseline: 2.1050x; 1.1219x over previous
//
#include <hip/hip_runtime.h>

#define THREADS 256

// ---------------- degree histogram ----------------
__global__ __launch_bounds__(THREADS) void deg_kernel(const int* __restrict__ dst, int E,
                                                      int* __restrict__ deg) {
    int e = blockIdx.x * blockDim.x + threadIdx.x;
    if (e < E) atomicAdd(&deg[dst[e]], 1);
}

// ---------------- 3-phase exclusive scan over deg (N <= 65536) ----------------
__global__ __launch_bounds__(THREADS) void scan1(const int* __restrict__ deg, int N,
                                                 int* __restrict__ bsum) {
    __shared__ int lds[THREADS];
    int t = threadIdx.x, b = blockIdx.x;
    int i = b * THREADS + t;
    lds[t] = (i < N) ? deg[i] : 0;
    __syncthreads();
    for (int off = THREADS / 2; off > 0; off >>= 1) {
        if (t < off) lds[t] += lds[t + off];
        __syncthreads();
    }
    if (t == 0) bsum[b] = lds[0];
}

__global__ __launch_bounds__(THREADS) void scan2(int* __restrict__ bsum, int nb) {
    __shared__ int lds[THREADS];
    int t = threadIdx.x;
    int v = (t < nb) ? bsum[t] : 0;
    lds[t] = v;
    __syncthreads();
    for (int off = 1; off < THREADS; off <<= 1) {
        int u = (t >= off) ? lds[t - off] : 0;
        __syncthreads();
        lds[t] += u;
        __syncthreads();
    }
    if (t < nb) bsum[t] = lds[t] - v;  // exclusive
}

__global__ __launch_bounds__(THREADS) void scan3(const int* __restrict__ deg, int N,
                                                 const int* __restrict__ bsum,
                                                 int* __restrict__ offs, int* __restrict__ cursor,
                                                 float* __restrict__ dinv) {
    __shared__ int lds[THREADS];
    int t = threadIdx.x, b = blockIdx.x;
    int i = b * THREADS + t;
    int v = (i < N) ? deg[i] : 0;
    lds[t] = v;
    __syncthreads();
    for (int off = 1; off < THREADS; off <<= 1) {
        int u = (t >= off) ? lds[t - off] : 0;
        __syncthreads();
        lds[t] += u;
        __syncthreads();
    }
    if (i < N) {
        int excl = bsum[b] + lds[t] - v;
        offs[i] = excl;
        cursor[i] = excl;
        dinv[i] = rsqrtf((float)v + 1.0f);  // +1 self-loop
    }
}

// ---------------- bucket cursor init: bcursor[b] = offs[b<<bshift] ----------------
__global__ __launch_bounds__(THREADS) void bcursor_init_kernel(const int* __restrict__ offs,
                                                               int N, int bshift, int nb,
                                                               int* __restrict__ bcursor) {
    int b = threadIdx.x;
    if (b < nb) bcursor[b] = offs[b << bshift];
}

// ---------------- P2: partition edges into 256-node buckets ----------------
// Segment-wise LDS histogram -> one global reservation atomic per (segment,bucket)
// -> bucket-contiguous staging writes. staging = src | dstlow<<16 (N<=65536).
#define SEG 2048
__global__ __launch_bounds__(THREADS) void partition_kernel(const int* __restrict__ src,
                                                            const int* __restrict__ dst, int E,
                                                            int bshift,
                                                            int* __restrict__ bcursor,
                                                            unsigned* __restrict__ staging) {
    __shared__ int hist[256];
    __shared__ int gbase[256];
    __shared__ int lcnt[256];
    int tid = threadIdx.x;
    int nseg = (E + SEG - 1) / SEG;
    for (int seg = blockIdx.x; seg < nseg; seg += gridDim.x) {
        int base = seg * SEG;
        int lim = min(E, base + SEG);
        hist[tid] = 0;
        __syncthreads();
        for (int i = base + tid; i < lim; i += THREADS)
            atomicAdd(&hist[dst[i] >> bshift], 1);
        __syncthreads();
        if (hist[tid] > 0) gbase[tid] = atomicAdd(&bcursor[tid], hist[tid]);
        lcnt[tid] = 0;
        __syncthreads();
        for (int i = base + tid; i < lim; i += THREADS) {
            int d = dst[i];
            int b = d >> bshift;
            int p = gbase[b] + atomicAdd(&lcnt[b], 1);
            staging[p] = (unsigned)src[i] | ((unsigned)(d - (b << bshift)) << 16);
        }
        __syncthreads();  // protect hist/gbase/lcnt before next segment
    }
}

// ---------------- P3: per-bucket local CSR fill (writes stay in a ~64KB window) ---
__global__ __launch_bounds__(THREADS) void local_fill_kernel(const unsigned* __restrict__ staging,
                                                             const int* __restrict__ offs,
                                                             int* __restrict__ cursor,
                                                             int E, int N, int bshift, int nb,
                                                             int* __restrict__ csr) {
    int b = (int)(blockIdx.x >> 3);   // bucket
    int sub = (int)(blockIdx.x & 7);  // 8 sub-blocks per bucket
    if (b >= nb) return;
    int start = offs[b << bshift];
    int nxt = (b + 1) << bshift;
    int end = (nxt >= N) ? E : offs[nxt];
    int nodebase = b << bshift;
    for (int i = start + sub * THREADS + threadIdx.x; i < end; i += 8 * THREADS) {
        unsigned v = staging[i];
        int node = nodebase + (int)(v >> 16);
        int pos = atomicAdd(&cursor[node], 1);
        csr[pos] = (int)(v & 0xFFFFu);
    }
}

// ---------------- original one-shot fill (fallback path) ----------------
__global__ __launch_bounds__(THREADS) void fill_kernel(const int* __restrict__ src,
                                                       const int* __restrict__ dst, int E,
                                                       int* __restrict__ cursor,
                                                       int* __restrict__ csr) {
    int e = blockIdx.x * blockDim.x + threadIdx.x;
    if (e < E) {
        int pos = atomicAdd(&cursor[dst[e]], 1);
        csr[pos] = src[e];
    }
}

// ---------------- pull aggregation: wave per node, lane per feature ----------------
__global__ __launch_bounds__(THREADS) void gather_kernel(const float* __restrict__ x,
                                                         const int* __restrict__ offs,
                                                         const int* __restrict__ deg,
                                                         const int* __restrict__ csr,
                                                         const float* __restrict__ dinv,
                                                         float* __restrict__ out, int N) {
    int lane = threadIdx.x & 63;
    int node = __builtin_amdgcn_readfirstlane(
        (int)((blockIdx.x * blockDim.x + threadIdx.x) >> 6));
    if (node >= N) return;
    float dd = dinv[node];
    float acc = dd * x[((size_t)node << 6) + lane];  // self-loop (final *dd -> dd^2)
    int start = offs[node];
    int cnt = deg[node];
    const int* __restrict__ row = csr + start;
    int j = 0;
    for (; j + 4 <= cnt; j += 4) {
        int s0 = __builtin_amdgcn_readfirstlane(row[j + 0]);
        int s1 = __builtin_amdgcn_readfirstlane(row[j + 1]);
        int s2 = __builtin_amdgcn_readfirstlane(row[j + 2]);
        int s3 = __builtin_amdgcn_readfirstlane(row[j + 3]);
        float w0 = dinv[s0], w1 = dinv[s1], w2 = dinv[s2], w3 = dinv[s3];
        float v0 = x[((size_t)s0 << 6) + lane];
        float v1 = x[((size_t)s1 << 6) + lane];
        float v2 = x[((size_t)s2 << 6) + lane];
        float v3 = x[((size_t)s3 << 6) + lane];
        acc += w0 * v0 + w1 * v1 + w2 * v2 + w3 * v3;
    }
    for (; j < cnt; ++j) {
        int s = __builtin_amdgcn_readfirstlane(row[j]);
        acc += dinv[s] * x[((size_t)s << 6) + lane];
    }
    out[((size_t)node << 6) + lane] = dd * acc;
}

// ---------------- LDS-tiled in-place matmul io = io @ W, fused stats ----------------
// k-loop rolled (#pragma unroll 1): full unroll spilled (VGPR=256, 200MB scratch, R4).
#define AT_LD 68
__global__ __launch_bounds__(THREADS) void matmul_stats_kernel(float* __restrict__ io,
                                                               const float* __restrict__ W,
                                                               float* __restrict__ stats, int N) {
    __shared__ float Wl[64 * 64];    // Wl[k*64+c]
    __shared__ float At[64 * AT_LD]; // At[r*AT_LD+k]
    __shared__ float bred[128];
    int tid = threadIdx.x;

    for (int i = tid; i < 1024; i += THREADS)
        ((float4*)Wl)[i] = ((const float4*)W)[i];

    int c0 = (tid & 15) * 4;
    int r0 = (tid >> 4) * 4;
    int ntiles = (N + 63) >> 6;
    float sums[4] = {0.f, 0.f, 0.f, 0.f};
    float sqs[4] = {0.f, 0.f, 0.f, 0.f};

    for (int tile = blockIdx.x; tile < ntiles; tile += gridDim.x) {
        int base = tile << 6;
        __syncthreads();
        for (int g = tid; g < 1024; g += THREADS) {
            int r = g >> 4, cc = (g & 15) << 2;
            int rowi = base + r;
            float4 v = {0.f, 0.f, 0.f, 0.f};
            if (rowi < N) v = *(const float4*)(io + ((size_t)rowi << 6) + cc);
            *(float4*)(&At[r * AT_LD + cc]) = v;
        }
        __syncthreads();

        float acc[4][4] = {};
#pragma unroll 1
        for (int k0 = 0; k0 < 64; k0 += 4) {
            float4 a[4], wf[4];
#pragma unroll
            for (int i = 0; i < 4; ++i)
                a[i] = *(const float4*)(&At[(r0 + i) * AT_LD + k0]);
#pragma unroll
            for (int q = 0; q < 4; ++q)
                wf[q] = *(const float4*)(&Wl[(k0 + q) * 64 + c0]);
#pragma unroll
            for (int i = 0; i < 4; ++i) {
                const float* ap = (const float*)&a[i];
#pragma unroll
                for (int j = 0; j < 4; ++j) {
                    acc[i][j] += ap[0] * ((const float*)&wf[0])[j] +
                                 ap[1] * ((const float*)&wf[1])[j] +
                                 ap[2] * ((const float*)&wf[2])[j] +
                                 ap[3] * ((const float*)&wf[3])[j];
                }
            }
        }

#pragma unroll
        for (int i = 0; i < 4; ++i) {
            int rowi = base + r0 + i;
            if (rowi < N) {
                float4 o = {acc[i][0], acc[i][1], acc[i][2], acc[i][3]};
                *(float4*)(io + ((size_t)rowi << 6) + c0) = o;
#pragma unroll
                for (int j = 0; j < 4; ++j) {
                    sums[j] += acc[i][j];
                    sqs[j] += acc[i][j] * acc[i][j];
                }
            }
        }
    }

    __syncthreads();
    if (tid < 128) bred[tid] = 0.f;
    __syncthreads();
#pragma unroll
    for (int j = 0; j < 4; ++j) {
        atomicAdd(&bred[c0 + j], sums[j]);
        atomicAdd(&bred[64 + c0 + j], sqs[j]);
    }
    __syncthreads();
    if (tid < 128) atomicAdd(&stats[tid], bred[tid]);
}

// ---------------- BN + ReLU in place ----------------
__global__ __launch_bounds__(THREADS) void bn_relu_kernel(float* __restrict__ io,
                                                          const float* __restrict__ stats,
                                                          const float* __restrict__ gamma,
                                                          const float* __restrict__ beta,
                                                          int n4, float invN) {
    int t = blockIdx.x * blockDim.x + threadIdx.x;
    if (t >= n4) return;
    int f0 = (t & 15) * 4;
    float4 v = ((const float4*)io)[t];
    float vv[4] = {v.x, v.y, v.z, v.w};
    float o[4];
#pragma unroll
    for (int j = 0; j < 4; ++j) {
        int f = f0 + j;
        float mean = stats[f] * invN;
        float var = stats[64 + f] * invN - mean * mean;
        float scale = gamma[f] * rsqrtf(var + 1e-5f);
        float shift = beta[f] - mean * scale;
        float y = vv[j] * scale + shift;
        o[j] = y > 0.f ? y : 0.f;
    }
    float4 r = {o[0], o[1], o[2], o[3]};
    ((float4*)io)[t] = r;
}

// ---------------- fallback (push path) kernels ----------------
__global__ __launch_bounds__(THREADS) void dinv_kernel(const int* __restrict__ deg,
                                                       float* __restrict__ dinv, int N) {
    int i = blockIdx.x * blockDim.x + threadIdx.x;
    if (i < N) dinv[i] = rsqrtf((float)deg[i] + 1.0f);
}

__global__ __launch_bounds__(THREADS) void selfloop_kernel(const float4* __restrict__ x4,
                                                           const float* __restrict__ dinv,
                                                           float4* __restrict__ out4, int n4) {
    int t = blockIdx.x * blockDim.x + threadIdx.x;
    if (t >= n4) return;
    int node = t >> 4;
    float s = dinv[node];
    s *= s;
    float4 v = x4[t];
    v.x *= s; v.y *= s; v.z *= s; v.w *= s;
    out4[t] = v;
}

__global__ __launch_bounds__(THREADS) void scatter_kernel(const int* __restrict__ src,
                                                          const int* __restrict__ dst, int E,
                                                          const float* __restrict__ x,
                                                          const float* __restrict__ dinv,
                                                          float* __restrict__ out) {
    int lane = threadIdx.x & 63;
    int wave = (blockIdx.x * blockDim.x + threadIdx.x) >> 6;
    int nwaves = (gridDim.x * blockDim.x) >> 6;
    for (int e = wave; e < E; e += nwaves) {
        int s = src[e];
        int d = dst[e];
        float nrm = dinv[s] * dinv[d];
        atomicAdd(&out[d * 64 + lane], x[s * 64 + lane] * nrm);
    }
}

extern "C" void kernel_launch(void* const* d_in, const int* in_sizes, int n_in,
                              void* d_out, int out_size, void* d_ws, size_t ws_size,
                              hipStream_t stream) {
    const float* x     = (const float*)d_in[0];
    const int*   edges = (const int*)d_in[1];
    const float* W     = (const float*)d_in[2];
    // d_in[3] = b cancels exactly in training-mode BN
    const float* gamma = (const float*)d_in[4];
    const float* beta  = (const float*)d_in[5];
    float* out = (float*)d_out;

    const int N = in_sizes[0] / 64;
    const int E = in_sizes[1] / 2;
    const int* src = edges;
    const int* dst = edges + E;
    const int n4 = N * 16;
    const int nb_scan = (N + THREADS - 1) / THREADS;

    char* ws = (char*)d_ws;
    // layout: deg[N] | offs[N] | cursor[N] | dinv[N] | stats[128] | bsum[256] |
    //         bcursor[256] | csr[E] | staging[E] (u32, bucketed path only)
    size_t need_csr  = (size_t)16 * N + 512 + 1024 + 1024 + (size_t)4 * E;
    size_t need_full = need_csr + (size_t)4 * E;

    if (ws_size >= need_csr && nb_scan <= THREADS) {
        int*   deg     = (int*)ws;
        int*   offs    = deg + N;
        int*   cursor  = offs + N;
        float* dinv    = (float*)(cursor + N);
        float* stats   = dinv + N;
        int*   bsum    = (int*)(stats + 128);
        int*   bcursor = bsum + 256;
        int*   csr     = bcursor + 256;
        unsigned* staging = (unsigned*)(csr + E);

        hipMemsetAsync(deg, 0, (size_t)4 * N, stream);
        hipMemsetAsync(stats, 0, 512, stream);

        deg_kernel<<<(E + THREADS - 1) / THREADS, THREADS, 0, stream>>>(dst, E, deg);
        scan1<<<nb_scan, THREADS, 0, stream>>>(deg, N, bsum);
        scan2<<<1, THREADS, 0, stream>>>(bsum, nb_scan);
        scan3<<<nb_scan, THREADS, 0, stream>>>(deg, N, bsum, offs, cursor, dinv);

        bool bucketed = (N <= 65536) && (ws_size >= need_full);
        if (bucketed) {
            const int bshift = 8;                 // 256 nodes per bucket
            const int nb = (N + 255) >> 8;        // <= 256
            bcursor_init_kernel<<<1, THREADS, 0, stream>>>(offs, N, bshift, nb, bcursor);
            int nseg = (E + SEG - 1) / SEG;
            partition_kernel<<<(nseg < 2048 ? nseg : 2048), THREADS, 0, stream>>>(
                src, dst, E, bshift, bcursor, staging);
            local_fill_kernel<<<nb * 8, THREADS, 0, stream>>>(staging, offs, cursor, E, N,
                                                              bshift, nb, csr);
        } else {
            fill_kernel<<<(E + THREADS - 1) / THREADS, THREADS, 0, stream>>>(src, dst, E,
                                                                             cursor, csr);
        }

        gather_kernel<<<(N * 64 + THREADS - 1) / THREADS, THREADS, 0, stream>>>(
            x, offs, deg, csr, dinv, out, N);
        int ntiles = (N + 63) >> 6;
        matmul_stats_kernel<<<(ntiles < 1024 ? ntiles : 1024), THREADS, 0, stream>>>(
            out, W, stats, N);
        bn_relu_kernel<<<(n4 + THREADS - 1) / THREADS, THREADS, 0, stream>>>(
            out, stats, gamma, beta, n4, 1.0f / (float)N);
    } else {
        // fallback: push path (ws: deg[N] | stats[128] | dinv[N])
        int*   deg   = (int*)ws;
        float* stats = (float*)(ws + (size_t)N * 4);
        float* dinv  = (float*)(ws + (size_t)N * 4 + 512);

        hipMemsetAsync(ws, 0, (size_t)N * 4 + 512, stream);
        deg_kernel<<<(E + THREADS - 1) / THREADS, THREADS, 0, stream>>>(dst, E, deg);
        dinv_kernel<<<(N + THREADS - 1) / THREADS, THREADS, 0, stream>>>(deg, dinv, N);
        selfloop_kernel<<<(n4 + THREADS - 1) / THREADS, THREADS, 0, stream>>>(
            (const float4*)x, dinv, (float4*)out, n4);
        scatter_kernel<<<1024, THREADS, 0, stream>>>(src, dst, E, x, dinv, out);
        matmul_stats_kernel<<<512, THREADS, 0, stream>>>(out, W, stats, N);
        bn_relu_kernel<<<(n4 + THREADS - 1) / THREADS, THREADS, 0, stream>>>(
            out, stats, gamma, beta, n4, 1.0f / (float)N);
    }
}

// Round 7
// 192.305 us; speedup vs baseline: 2.1434x; 1.0182x over previous
//
#include <hip/hip_runtime.h>

#define THREADS 256

// ---------------- degree histogram ----------------
__global__ __launch_bounds__(THREADS) void deg_kernel(const int* __restrict__ dst, int E,
                                                      int* __restrict__ deg) {
    int e = blockIdx.x * blockDim.x + threadIdx.x;
    if (e < E) atomicAdd(&deg[dst[e]], 1);
}

// ---------------- x (f32) -> xh (bf16 as ushort), RNE ----------------
__global__ __launch_bounds__(THREADS) void convert_kernel(const float4* __restrict__ x4,
                                                          ushort* __restrict__ xh, int n4) {
    int t = blockIdx.x * blockDim.x + threadIdx.x;
    if (t >= n4) return;
    float4 v = x4[t];
    const float* f = (const float*)&v;
    ushort u[4];
#pragma unroll
    for (int k = 0; k < 4; ++k) {
        unsigned b = __float_as_uint(f[k]);
        u[k] = (ushort)((b + 0x7FFFu + ((b >> 16) & 1u)) >> 16);  // round-nearest-even
    }
    *(ushort4*)(&xh[t * 4]) = make_ushort4(u[0], u[1], u[2], u[3]);
}

// ---------------- 3-phase exclusive scan over deg (N <= 65536) ----------------
__global__ __launch_bounds__(THREADS) void scan1(const int* __restrict__ deg, int N,
                                                 int* __restrict__ bsum) {
    __shared__ int lds[THREADS];
    int t = threadIdx.x, b = blockIdx.x;
    int i = b * THREADS + t;
    lds[t] = (i < N) ? deg[i] : 0;
    __syncthreads();
    for (int off = THREADS / 2; off > 0; off >>= 1) {
        if (t < off) lds[t] += lds[t + off];
        __syncthreads();
    }
    if (t == 0) bsum[b] = lds[0];
}

__global__ __launch_bounds__(THREADS) void scan2(int* __restrict__ bsum, int nb) {
    __shared__ int lds[THREADS];
    int t = threadIdx.x;
    int v = (t < nb) ? bsum[t] : 0;
    lds[t] = v;
    __syncthreads();
    for (int off = 1; off < THREADS; off <<= 1) {
        int u = (t >= off) ? lds[t - off] : 0;
        __syncthreads();
        lds[t] += u;
        __syncthreads();
    }
    if (t < nb) bsum[t] = lds[t] - v;  // exclusive
}

__global__ __launch_bounds__(THREADS) void scan3(const int* __restrict__ deg, int N,
                                                 const int* __restrict__ bsum,
                                                 int* __restrict__ offs, int* __restrict__ cursor,
                                                 float* __restrict__ dinv,
                                                 int* __restrict__ bcursor) {
    __shared__ int lds[THREADS];
    int t = threadIdx.x, b = blockIdx.x;
    int i = b * THREADS + t;
    int v = (i < N) ? deg[i] : 0;
    lds[t] = v;
    __syncthreads();
    for (int off = 1; off < THREADS; off <<= 1) {
        int u = (t >= off) ? lds[t - off] : 0;
        __syncthreads();
        lds[t] += u;
        __syncthreads();
    }
    if (i < N) {
        int excl = bsum[b] + lds[t] - v;
        offs[i] = excl;
        cursor[i] = excl;
        dinv[i] = rsqrtf((float)v + 1.0f);  // +1 self-loop
        if ((i & 255) == 0) bcursor[i >> 8] = excl;  // bucket cursor init (bshift=8)
    }
}

// ---------------- P2: partition edges into 256-node buckets ----------------
#define SEG 2048
__global__ __launch_bounds__(THREADS) void partition_kernel(const int* __restrict__ src,
                                                            const int* __restrict__ dst, int E,
                                                            int bshift,
                                                            int* __restrict__ bcursor,
                                                            unsigned* __restrict__ staging) {
    __shared__ int hist[256];
    __shared__ int gbase[256];
    __shared__ int lcnt[256];
    int tid = threadIdx.x;
    int nseg = (E + SEG - 1) / SEG;
    for (int seg = blockIdx.x; seg < nseg; seg += gridDim.x) {
        int base = seg * SEG;
        int lim = min(E, base + SEG);
        hist[tid] = 0;
        __syncthreads();
        for (int i = base + tid; i < lim; i += THREADS)
            atomicAdd(&hist[dst[i] >> bshift], 1);
        __syncthreads();
        if (hist[tid] > 0) gbase[tid] = atomicAdd(&bcursor[tid], hist[tid]);
        lcnt[tid] = 0;
        __syncthreads();
        for (int i = base + tid; i < lim; i += THREADS) {
            int d = dst[i];
            int b = d >> bshift;
            int p = gbase[b] + atomicAdd(&lcnt[b], 1);
            staging[p] = (unsigned)src[i] | ((unsigned)(d - (b << bshift)) << 16);
        }
        __syncthreads();
    }
}

// ---------------- P3: per-bucket local CSR fill ----------------
__global__ __launch_bounds__(THREADS) void local_fill_kernel(const unsigned* __restrict__ staging,
                                                             const int* __restrict__ offs,
                                                             int* __restrict__ cursor,
                                                             int E, int N, int bshift, int nb,
                                                             int* __restrict__ csr) {
    int b = (int)(blockIdx.x >> 3);
    int sub = (int)(blockIdx.x & 7);
    if (b >= nb) return;
    int start = offs[b << bshift];
    int nxt = (b + 1) << bshift;
    int end = (nxt >= N) ? E : offs[nxt];
    int nodebase = b << bshift;
    for (int i = start + sub * THREADS + threadIdx.x; i < end; i += 8 * THREADS) {
        unsigned v = staging[i];
        int node = nodebase + (int)(v >> 16);
        int pos = atomicAdd(&cursor[node], 1);
        csr[pos] = (int)(v & 0xFFFFu);
    }
}

// ---------------- one-shot fill (fallback) ----------------
__global__ __launch_bounds__(THREADS) void fill_kernel(const int* __restrict__ src,
                                                       const int* __restrict__ dst, int E,
                                                       int* __restrict__ cursor,
                                                       int* __restrict__ csr) {
    int e = blockIdx.x * blockDim.x + threadIdx.x;
    if (e < E) {
        int pos = atomicAdd(&cursor[dst[e]], 1);
        csr[pos] = src[e];
    }
}

// ---------------- pull aggregation from bf16 x: wave/node, lane/feature ----------------
__device__ __forceinline__ float bf2f(ushort u) {
    return __uint_as_float(((unsigned)u) << 16);
}

__global__ __launch_bounds__(THREADS) void gather_bf16_kernel(const ushort* __restrict__ xh,
                                                              const int* __restrict__ offs,
                                                              const int* __restrict__ deg,
                                                              const int* __restrict__ csr,
                                                              const float* __restrict__ dinv,
                                                              float* __restrict__ out, int N) {
    int lane = threadIdx.x & 63;
    int node = __builtin_amdgcn_readfirstlane(
        (int)((blockIdx.x * blockDim.x + threadIdx.x) >> 6));
    if (node >= N) return;
    float dd = dinv[node];
    float acc = dd * bf2f(xh[((size_t)node << 6) + lane]);  // self-loop
    int start = offs[node];
    int cnt = deg[node];
    const int* __restrict__ row = csr + start;
    int j = 0;
    for (; j + 8 <= cnt; j += 8) {
        int s0 = __builtin_amdgcn_readfirstlane(row[j + 0]);
        int s1 = __builtin_amdgcn_readfirstlane(row[j + 1]);
        int s2 = __builtin_amdgcn_readfirstlane(row[j + 2]);
        int s3 = __builtin_amdgcn_readfirstlane(row[j + 3]);
        int s4 = __builtin_amdgcn_readfirstlane(row[j + 4]);
        int s5 = __builtin_amdgcn_readfirstlane(row[j + 5]);
        int s6 = __builtin_amdgcn_readfirstlane(row[j + 6]);
        int s7 = __builtin_amdgcn_readfirstlane(row[j + 7]);
        float w0 = dinv[s0], w1 = dinv[s1], w2 = dinv[s2], w3 = dinv[s3];
        float w4 = dinv[s4], w5 = dinv[s5], w6 = dinv[s6], w7 = dinv[s7];
        ushort u0 = xh[((size_t)s0 << 6) + lane];
        ushort u1 = xh[((size_t)s1 << 6) + lane];
        ushort u2 = xh[((size_t)s2 << 6) + lane];
        ushort u3 = xh[((size_t)s3 << 6) + lane];
        ushort u4 = xh[((size_t)s4 << 6) + lane];
        ushort u5 = xh[((size_t)s5 << 6) + lane];
        ushort u6 = xh[((size_t)s6 << 6) + lane];
        ushort u7 = xh[((size_t)s7 << 6) + lane];
        acc += w0 * bf2f(u0) + w1 * bf2f(u1) + w2 * bf2f(u2) + w3 * bf2f(u3) +
               w4 * bf2f(u4) + w5 * bf2f(u5) + w6 * bf2f(u6) + w7 * bf2f(u7);
    }
    for (; j < cnt; ++j) {
        int s = __builtin_amdgcn_readfirstlane(row[j]);
        acc += dinv[s] * bf2f(xh[((size_t)s << 6) + lane]);
    }
    out[((size_t)node << 6) + lane] = dd * acc;
}

// ---------------- f32 gather (fallback when no room for xh) ----------------
__global__ __launch_bounds__(THREADS) void gather_kernel(const float* __restrict__ x,
                                                         const int* __restrict__ offs,
                                                         const int* __restrict__ deg,
                                                         const int* __restrict__ csr,
                                                         const float* __restrict__ dinv,
                                                         float* __restrict__ out, int N) {
    int lane = threadIdx.x & 63;
    int node = __builtin_amdgcn_readfirstlane(
        (int)((blockIdx.x * blockDim.x + threadIdx.x) >> 6));
    if (node >= N) return;
    float dd = dinv[node];
    float acc = dd * x[((size_t)node << 6) + lane];
    int start = offs[node];
    int cnt = deg[node];
    const int* __restrict__ row = csr + start;
    int j = 0;
    for (; j + 4 <= cnt; j += 4) {
        int s0 = __builtin_amdgcn_readfirstlane(row[j + 0]);
        int s1 = __builtin_amdgcn_readfirstlane(row[j + 1]);
        int s2 = __builtin_amdgcn_readfirstlane(row[j + 2]);
        int s3 = __builtin_amdgcn_readfirstlane(row[j + 3]);
        float w0 = dinv[s0], w1 = dinv[s1], w2 = dinv[s2], w3 = dinv[s3];
        float v0 = x[((size_t)s0 << 6) + lane];
        float v1 = x[((size_t)s1 << 6) + lane];
        float v2 = x[((size_t)s2 << 6) + lane];
        float v3 = x[((size_t)s3 << 6) + lane];
        acc += w0 * v0 + w1 * v1 + w2 * v2 + w3 * v3;
    }
    for (; j < cnt; ++j) {
        int s = __builtin_amdgcn_readfirstlane(row[j]);
        acc += dinv[s] * x[((size_t)s << 6) + lane];
    }
    out[((size_t)node << 6) + lane] = dd * acc;
}

// ---------------- LDS-tiled in-place matmul io = io @ W, fused stats ----------------
// k-loop rolled (#pragma unroll 1): full unroll spilled (VGPR=256, R4).
#define AT_LD 68
__global__ __launch_bounds__(THREADS) void matmul_stats_kernel(float* __restrict__ io,
                                                               const float* __restrict__ W,
                                                               float* __restrict__ stats, int N) {
    __shared__ float Wl[64 * 64];
    __shared__ float At[64 * AT_LD];
    __shared__ float bred[128];
    int tid = threadIdx.x;

    for (int i = tid; i < 1024; i += THREADS)
        ((float4*)Wl)[i] = ((const float4*)W)[i];

    int c0 = (tid & 15) * 4;
    int r0 = (tid >> 4) * 4;
    int ntiles = (N + 63) >> 6;
    float sums[4] = {0.f, 0.f, 0.f, 0.f};
    float sqs[4] = {0.f, 0.f, 0.f, 0.f};

    for (int tile = blockIdx.x; tile < ntiles; tile += gridDim.x) {
        int base = tile << 6;
        __syncthreads();
        for (int g = tid; g < 1024; g += THREADS) {
            int r = g >> 4, cc = (g & 15) << 2;
            int rowi = base + r;
            float4 v = {0.f, 0.f, 0.f, 0.f};
            if (rowi < N) v = *(const float4*)(io + ((size_t)rowi << 6) + cc);
            *(float4*)(&At[r * AT_LD + cc]) = v;
        }
        __syncthreads();

        float acc[4][4] = {};
#pragma unroll 1
        for (int k0 = 0; k0 < 64; k0 += 4) {
            float4 a[4], wf[4];
#pragma unroll
            for (int i = 0; i < 4; ++i)
                a[i] = *(const float4*)(&At[(r0 + i) * AT_LD + k0]);
#pragma unroll
            for (int q = 0; q < 4; ++q)
                wf[q] = *(const float4*)(&Wl[(k0 + q) * 64 + c0]);
#pragma unroll
            for (int i = 0; i < 4; ++i) {
                const float* ap = (const float*)&a[i];
#pragma unroll
                for (int j = 0; j < 4; ++j) {
                    acc[i][j] += ap[0] * ((const float*)&wf[0])[j] +
                                 ap[1] * ((const float*)&wf[1])[j] +
                                 ap[2] * ((const float*)&wf[2])[j] +
                                 ap[3] * ((const float*)&wf[3])[j];
                }
            }
        }

#pragma unroll
        for (int i = 0; i < 4; ++i) {
            int rowi = base + r0 + i;
            if (rowi < N) {
                float4 o = {acc[i][0], acc[i][1], acc[i][2], acc[i][3]};
                *(float4*)(io + ((size_t)rowi << 6) + c0) = o;
#pragma unroll
                for (int j = 0; j < 4; ++j) {
                    sums[j] += acc[i][j];
                    sqs[j] += acc[i][j] * acc[i][j];
                }
            }
        }
    }

    __syncthreads();
    if (tid < 128) bred[tid] = 0.f;
    __syncthreads();
#pragma unroll
    for (int j = 0; j < 4; ++j) {
        atomicAdd(&bred[c0 + j], sums[j]);
        atomicAdd(&bred[64 + c0 + j], sqs[j]);
    }
    __syncthreads();
    if (tid < 128) atomicAdd(&stats[tid], bred[tid]);
}

// ---------------- BN + ReLU in place ----------------
__global__ __launch_bounds__(THREADS) void bn_relu_kernel(float* __restrict__ io,
                                                          const float* __restrict__ stats,
                                                          const float* __restrict__ gamma,
                                                          const float* __restrict__ beta,
                                                          int n4, float invN) {
    int t = blockIdx.x * blockDim.x + threadIdx.x;
    if (t >= n4) return;
    int f0 = (t & 15) * 4;
    float4 v = ((const float4*)io)[t];
    float vv[4] = {v.x, v.y, v.z, v.w};
    float o[4];
#pragma unroll
    for (int j = 0; j < 4; ++j) {
        int f = f0 + j;
        float mean = stats[f] * invN;
        float var = stats[64 + f] * invN - mean * mean;
        float scale = gamma[f] * rsqrtf(var + 1e-5f);
        float shift = beta[f] - mean * scale;
        float y = vv[j] * scale + shift;
        o[j] = y > 0.f ? y : 0.f;
    }
    float4 r = {o[0], o[1], o[2], o[3]};
    ((float4*)io)[t] = r;
}

// ---------------- fallback (push path) kernels ----------------
__global__ __launch_bounds__(THREADS) void dinv_kernel(const int* __restrict__ deg,
                                                       float* __restrict__ dinv, int N) {
    int i = blockIdx.x * blockDim.x + threadIdx.x;
    if (i < N) dinv[i] = rsqrtf((float)deg[i] + 1.0f);
}

__global__ __launch_bounds__(THREADS) void selfloop_kernel(const float4* __restrict__ x4,
                                                           const float* __restrict__ dinv,
                                                           float4* __restrict__ out4, int n4) {
    int t = blockIdx.x * blockDim.x + threadIdx.x;
    if (t >= n4) return;
    int node = t >> 4;
    float s = dinv[node];
    s *= s;
    float4 v = x4[t];
    v.x *= s; v.y *= s; v.z *= s; v.w *= s;
    out4[t] = v;
}

__global__ __launch_bounds__(THREADS) void scatter_kernel(const int* __restrict__ src,
                                                          const int* __restrict__ dst, int E,
                                                          const float* __restrict__ x,
                                                          const float* __restrict__ dinv,
                                                          float* __restrict__ out) {
    int lane = threadIdx.x & 63;
    int wave = (blockIdx.x * blockDim.x + threadIdx.x) >> 6;
    int nwaves = (gridDim.x * blockDim.x) >> 6;
    for (int e = wave; e < E; e += nwaves) {
        int s = src[e];
        int d = dst[e];
        float nrm = dinv[s] * dinv[d];
        atomicAdd(&out[d * 64 + lane], x[s * 64 + lane] * nrm);
    }
}

extern "C" void kernel_launch(void* const* d_in, const int* in_sizes, int n_in,
                              void* d_out, int out_size, void* d_ws, size_t ws_size,
                              hipStream_t stream) {
    const float* x     = (const float*)d_in[0];
    const int*   edges = (const int*)d_in[1];
    const float* W     = (const float*)d_in[2];
    // d_in[3] = b cancels exactly in training-mode BN
    const float* gamma = (const float*)d_in[4];
    const float* beta  = (const float*)d_in[5];
    float* out = (float*)d_out;

    const int N = in_sizes[0] / 64;
    const int E = in_sizes[1] / 2;
    const int* src = edges;
    const int* dst = edges + E;
    const int n4 = N * 16;
    const int nb_scan = (N + THREADS - 1) / THREADS;

    char* ws = (char*)d_ws;
    // layout: deg[N] | stats[128] | offs[N] | cursor[N] | dinv[N] | bsum[256] |
    //         bcursor[256] | csr[E] | staging[E] | xh[N*64 ushort]
    size_t off_deg = 0;
    size_t off_stats = off_deg + (size_t)4 * N;
    size_t off_offs = off_stats + 512;
    size_t off_cursor = off_offs + (size_t)4 * N;
    size_t off_dinv = off_cursor + (size_t)4 * N;
    size_t off_bsum = off_dinv + (size_t)4 * N;
    size_t off_bcursor = off_bsum + 1024;
    size_t off_csr = off_bcursor + 1024;
    size_t off_staging = off_csr + (size_t)4 * E;
    size_t off_xh = (off_staging + (size_t)4 * E + 15) & ~(size_t)15;

    size_t need_csr = off_staging;                       // csr path, no bucketing
    size_t need_full = off_staging + (size_t)4 * E;      // + staging
    size_t need_bf16 = off_xh + (size_t)128 * N;         // + xh

    if (ws_size >= need_csr && nb_scan <= THREADS) {
        int*   deg     = (int*)(ws + off_deg);
        float* stats   = (float*)(ws + off_stats);
        int*   offs    = (int*)(ws + off_offs);
        int*   cursor  = (int*)(ws + off_cursor);
        float* dinv    = (float*)(ws + off_dinv);
        int*   bsum    = (int*)(ws + off_bsum);
        int*   bcursor = (int*)(ws + off_bcursor);
        int*   csr     = (int*)(ws + off_csr);
        unsigned* staging = (unsigned*)(ws + off_staging);
        ushort* xh     = (ushort*)(ws + off_xh);

        bool bucketed = (N <= 65536) && (ws_size >= need_full);
        bool use_bf16 = (ws_size >= need_bf16);

        hipMemsetAsync(ws, 0, (size_t)4 * N + 512, stream);  // deg + stats contiguous

        if (use_bf16)
            convert_kernel<<<(n4 + THREADS - 1) / THREADS, THREADS, 0, stream>>>(
                (const float4*)x, xh, n4);

        deg_kernel<<<(E + THREADS - 1) / THREADS, THREADS, 0, stream>>>(dst, E, deg);
        scan1<<<nb_scan, THREADS, 0, stream>>>(deg, N, bsum);
        scan2<<<1, THREADS, 0, stream>>>(bsum, nb_scan);
        scan3<<<nb_scan, THREADS, 0, stream>>>(deg, N, bsum, offs, cursor, dinv, bcursor);

        if (bucketed) {
            const int bshift = 8;
            const int nb = (N + 255) >> 8;
            int nseg = (E + SEG - 1) / SEG;
            partition_kernel<<<(nseg < 2048 ? nseg : 2048), THREADS, 0, stream>>>(
                src, dst, E, bshift, bcursor, staging);
            local_fill_kernel<<<nb * 8, THREADS, 0, stream>>>(staging, offs, cursor, E, N,
                                                              bshift, nb, csr);
        } else {
            fill_kernel<<<(E + THREADS - 1) / THREADS, THREADS, 0, stream>>>(src, dst, E,
                                                                             cursor, csr);
        }

        if (use_bf16)
            gather_bf16_kernel<<<(N * 64 + THREADS - 1) / THREADS, THREADS, 0, stream>>>(
                xh, offs, deg, csr, dinv, out, N);
        else
            gather_kernel<<<(N * 64 + THREADS - 1) / THREADS, THREADS, 0, stream>>>(
                x, offs, deg, csr, dinv, out, N);

        int ntiles = (N + 63) >> 6;
        matmul_stats_kernel<<<(ntiles < 1024 ? ntiles : 1024), THREADS, 0, stream>>>(
            out, W, stats, N);
        bn_relu_kernel<<<(n4 + THREADS - 1) / THREADS, THREADS, 0, stream>>>(
            out, stats, gamma, beta, n4, 1.0f / (float)N);
    } else {
        // fallback: push path (ws: deg[N] | stats[128] | dinv[N])
        int*   deg   = (int*)ws;
        float* stats = (float*)(ws + (size_t)N * 4);
        float* dinv  = (float*)(ws + (size_t)N * 4 + 512);

        hipMemsetAsync(ws, 0, (size_t)N * 4 + 512, stream);
        deg_kernel<<<(E + THREADS - 1) / THREADS, THREADS, 0, stream>>>(dst, E, deg);
        dinv_kernel<<<(N + THREADS - 1) / THREADS, THREADS, 0, stream>>>(deg, dinv, N);
        selfloop_kernel<<<(n4 + THREADS - 1) / THREADS, THREADS, 0, stream>>>(
            (const float4*)x, dinv, (float4*)out, n4);
        scatter_kernel<<<1024, THREADS, 0, stream>>>(src, dst, E, x, dinv, out);
        matmul_stats_kernel<<<512, THREADS, 0, stream>>>(out, W, stats, N);
        bn_relu_kernel<<<(n4 + THREADS - 1) / THREADS, THREADS, 0, stream>>>(
            out, stats, gamma, beta, n4, 1.0f / (float)N);
    }
}

// Round 8
// 155.942 us; speedup vs baseline: 2.6432x; 1.2332x over previous
//
#include <hip/hip_runtime.h>

#define THREADS 256
#define SEG 2048

// ---------------- init: zero bucket counters + stats ----------------
__global__ __launch_bounds__(THREADS) void init_kernel(int* __restrict__ bcnt,
                                                       float* __restrict__ stats) {
    int t = threadIdx.x;
    bcnt[t] = 0;
    if (t < 128) stats[t] = 0.f;
}

// ---------------- x (f32) -> xh (bf16 as ushort), RNE ----------------
__global__ __launch_bounds__(THREADS) void convert_kernel(const float4* __restrict__ x4,
                                                          ushort* __restrict__ xh, int n4) {
    int t = blockIdx.x * blockDim.x + threadIdx.x;
    if (t >= n4) return;
    float4 v = x4[t];
    const float* f = (const float*)&v;
    ushort u[4];
#pragma unroll
    for (int k = 0; k < 4; ++k) {
        unsigned b = __float_as_uint(f[k]);
        u[k] = (ushort)((b + 0x7FFFu + ((b >> 16) & 1u)) >> 16);  // round-nearest-even
    }
    *(ushort4*)(&xh[t * 4]) = make_ushort4(u[0], u[1], u[2], u[3]);
}

// ---------------- bucket histogram: LDS-aggregated, 256 global atomics/block ----
__global__ __launch_bounds__(THREADS) void bhist_kernel(const int* __restrict__ dst, int E,
                                                        int* __restrict__ bcnt) {
    __shared__ int h[256];
    int tid = threadIdx.x;
    h[tid] = 0;
    __syncthreads();
    for (int i = blockIdx.x * blockDim.x + tid; i < E; i += gridDim.x * blockDim.x)
        atomicAdd(&h[dst[i] >> 8], 1);
    __syncthreads();
    if (h[tid] > 0) atomicAdd(&bcnt[tid], h[tid]);
}

// ---------------- bucket scan (1 block): bcnt -> boffs[257], bcursor ----------------
__global__ __launch_bounds__(THREADS) void bscan_kernel(const int* __restrict__ bcnt,
                                                        int* __restrict__ boffs,
                                                        int* __restrict__ bcursor) {
    __shared__ int lds[256];
    int t = threadIdx.x;
    int v = bcnt[t];
    lds[t] = v;
    __syncthreads();
    for (int off = 1; off < 256; off <<= 1) {
        int u = (t >= off) ? lds[t - off] : 0;
        __syncthreads();
        lds[t] += u;
        __syncthreads();
    }
    int excl = lds[t] - v;
    boffs[t] = excl;
    bcursor[t] = excl;
    if (t == 255) boffs[256] = lds[255];
}

// ---------------- P2: partition edges into 256-node buckets ----------------
// staging = src | dstlow<<16 (valid while N <= 65536)
__global__ __launch_bounds__(THREADS) void partition_kernel(const int* __restrict__ src,
                                                            const int* __restrict__ dst, int E,
                                                            int* __restrict__ bcursor,
                                                            unsigned* __restrict__ staging) {
    __shared__ int hist[256];
    __shared__ int gbase[256];
    __shared__ int lcnt[256];
    int tid = threadIdx.x;
    int nseg = (E + SEG - 1) / SEG;
    for (int seg = blockIdx.x; seg < nseg; seg += gridDim.x) {
        int base = seg * SEG;
        int lim = min(E, base + SEG);
        hist[tid] = 0;
        __syncthreads();
        for (int i = base + tid; i < lim; i += THREADS)
            atomicAdd(&hist[dst[i] >> 8], 1);
        __syncthreads();
        if (hist[tid] > 0) gbase[tid] = atomicAdd(&bcursor[tid], hist[tid]);
        lcnt[tid] = 0;
        __syncthreads();
        for (int i = base + tid; i < lim; i += THREADS) {
            int d = dst[i];
            int b = d >> 8;
            int p = gbase[b] + atomicAdd(&lcnt[b], 1);
            staging[p] = (unsigned)src[i] | ((unsigned)(d & 255) << 16);
        }
        __syncthreads();
    }
}

// ---------------- P3: per-bucket build: deg/offs/dinv + CSR fill, all LDS atomics ----
__global__ __launch_bounds__(THREADS) void bucket_build_kernel(const unsigned* __restrict__ staging,
                                                               const int* __restrict__ boffs,
                                                               int N,
                                                               int* __restrict__ deg,
                                                               int* __restrict__ offs,
                                                               float* __restrict__ dinv,
                                                               int* __restrict__ csr) {
    __shared__ int hist[256];
    __shared__ int lofs[256];
    __shared__ int lcur[256];
    int tid = threadIdx.x;
    int b = blockIdx.x;
    int s = boffs[b];
    int e = boffs[b + 1];

    hist[tid] = 0;
    __syncthreads();
    for (int i = s + tid; i < e; i += THREADS)
        atomicAdd(&hist[staging[i] >> 16], 1);
    __syncthreads();

    int v = hist[tid];
    lofs[tid] = v;
    __syncthreads();
    for (int off = 1; off < 256; off <<= 1) {
        int u = (tid >= off) ? lofs[tid - off] : 0;
        __syncthreads();
        lofs[tid] += u;
        __syncthreads();
    }
    int excl = lofs[tid] - v;

    int node = (b << 8) + tid;
    if (node < N) {
        deg[node] = v;
        offs[node] = s + excl;
        dinv[node] = rsqrtf((float)v + 1.0f);  // +1 self-loop
    }
    lcur[tid] = excl;
    __syncthreads();

    for (int i = s + tid; i < e; i += THREADS) {
        unsigned w = staging[i];
        int ln = (int)(w >> 16);
        int p = atomicAdd(&lcur[ln], 1);
        csr[s + p] = (int)(w & 0xFFFFu);
    }
}

// ---------------- pull aggregation from bf16 x: wave/node, lane/feature ----------------
__device__ __forceinline__ float bf2f(ushort u) {
    return __uint_as_float(((unsigned)u) << 16);
}

__global__ __launch_bounds__(THREADS) void gather_bf16_kernel(const ushort* __restrict__ xh,
                                                              const int* __restrict__ offs,
                                                              const int* __restrict__ deg,
                                                              const int* __restrict__ csr,
                                                              const float* __restrict__ dinv,
                                                              float* __restrict__ out, int N) {
    int lane = threadIdx.x & 63;
    int node = __builtin_amdgcn_readfirstlane(
        (int)((blockIdx.x * blockDim.x + threadIdx.x) >> 6));
    if (node >= N) return;
    float dd = dinv[node];
    float acc = dd * bf2f(xh[((size_t)node << 6) + lane]);  // self-loop
    int start = offs[node];
    int cnt = deg[node];
    const int* __restrict__ row = csr + start;
    int j = 0;
    for (; j + 8 <= cnt; j += 8) {
        int s0 = __builtin_amdgcn_readfirstlane(row[j + 0]);
        int s1 = __builtin_amdgcn_readfirstlane(row[j + 1]);
        int s2 = __builtin_amdgcn_readfirstlane(row[j + 2]);
        int s3 = __builtin_amdgcn_readfirstlane(row[j + 3]);
        int s4 = __builtin_amdgcn_readfirstlane(row[j + 4]);
        int s5 = __builtin_amdgcn_readfirstlane(row[j + 5]);
        int s6 = __builtin_amdgcn_readfirstlane(row[j + 6]);
        int s7 = __builtin_amdgcn_readfirstlane(row[j + 7]);
        float w0 = dinv[s0], w1 = dinv[s1], w2 = dinv[s2], w3 = dinv[s3];
        float w4 = dinv[s4], w5 = dinv[s5], w6 = dinv[s6], w7 = dinv[s7];
        ushort u0 = xh[((size_t)s0 << 6) + lane];
        ushort u1 = xh[((size_t)s1 << 6) + lane];
        ushort u2 = xh[((size_t)s2 << 6) + lane];
        ushort u3 = xh[((size_t)s3 << 6) + lane];
        ushort u4 = xh[((size_t)s4 << 6) + lane];
        ushort u5 = xh[((size_t)s5 << 6) + lane];
        ushort u6 = xh[((size_t)s6 << 6) + lane];
        ushort u7 = xh[((size_t)s7 << 6) + lane];
        acc += w0 * bf2f(u0) + w1 * bf2f(u1) + w2 * bf2f(u2) + w3 * bf2f(u3) +
               w4 * bf2f(u4) + w5 * bf2f(u5) + w6 * bf2f(u6) + w7 * bf2f(u7);
    }
    for (; j < cnt; ++j) {
        int s = __builtin_amdgcn_readfirstlane(row[j]);
        acc += dinv[s] * bf2f(xh[((size_t)s << 6) + lane]);
    }
    out[((size_t)node << 6) + lane] = dd * acc;
}

// ---------------- LDS-tiled in-place matmul io = io @ W, fused stats ----------------
// k-loop rolled (#pragma unroll 1): full unroll spilled (VGPR=256, R4).
#define AT_LD 68
__global__ __launch_bounds__(THREADS) void matmul_stats_kernel(float* __restrict__ io,
                                                               const float* __restrict__ W,
                                                               float* __restrict__ stats, int N) {
    __shared__ float Wl[64 * 64];
    __shared__ float At[64 * AT_LD];
    __shared__ float bred[128];
    int tid = threadIdx.x;

    for (int i = tid; i < 1024; i += THREADS)
        ((float4*)Wl)[i] = ((const float4*)W)[i];

    int c0 = (tid & 15) * 4;
    int r0 = (tid >> 4) * 4;
    int ntiles = (N + 63) >> 6;
    float sums[4] = {0.f, 0.f, 0.f, 0.f};
    float sqs[4] = {0.f, 0.f, 0.f, 0.f};

    for (int tile = blockIdx.x; tile < ntiles; tile += gridDim.x) {
        int base = tile << 6;
        __syncthreads();
        for (int g = tid; g < 1024; g += THREADS) {
            int r = g >> 4, cc = (g & 15) << 2;
            int rowi = base + r;
            float4 v = {0.f, 0.f, 0.f, 0.f};
            if (rowi < N) v = *(const float4*)(io + ((size_t)rowi << 6) + cc);
            *(float4*)(&At[r * AT_LD + cc]) = v;
        }
        __syncthreads();

        float acc[4][4] = {};
#pragma unroll 1
        for (int k0 = 0; k0 < 64; k0 += 4) {
            float4 a[4], wf[4];
#pragma unroll
            for (int i = 0; i < 4; ++i)
                a[i] = *(const float4*)(&At[(r0 + i) * AT_LD + k0]);
#pragma unroll
            for (int q = 0; q < 4; ++q)
                wf[q] = *(const float4*)(&Wl[(k0 + q) * 64 + c0]);
#pragma unroll
            for (int i = 0; i < 4; ++i) {
                const float* ap = (const float*)&a[i];
#pragma unroll
                for (int j = 0; j < 4; ++j) {
                    acc[i][j] += ap[0] * ((const float*)&wf[0])[j] +
                                 ap[1] * ((const float*)&wf[1])[j] +
                                 ap[2] * ((const float*)&wf[2])[j] +
                                 ap[3] * ((const float*)&wf[3])[j];
                }
            }
        }

#pragma unroll
        for (int i = 0; i < 4; ++i) {
            int rowi = base + r0 + i;
            if (rowi < N) {
                float4 o = {acc[i][0], acc[i][1], acc[i][2], acc[i][3]};
                *(float4*)(io + ((size_t)rowi << 6) + c0) = o;
#pragma unroll
                for (int j = 0; j < 4; ++j) {
                    sums[j] += acc[i][j];
                    sqs[j] += acc[i][j] * acc[i][j];
                }
            }
        }
    }

    __syncthreads();
    if (tid < 128) bred[tid] = 0.f;
    __syncthreads();
#pragma unroll
    for (int j = 0; j < 4; ++j) {
        atomicAdd(&bred[c0 + j], sums[j]);
        atomicAdd(&bred[64 + c0 + j], sqs[j]);
    }
    __syncthreads();
    if (tid < 128) atomicAdd(&stats[tid], bred[tid]);
}

// ---------------- BN + ReLU in place ----------------
__global__ __launch_bounds__(THREADS) void bn_relu_kernel(float* __restrict__ io,
                                                          const float* __restrict__ stats,
                                                          const float* __restrict__ gamma,
                                                          const float* __restrict__ beta,
                                                          int n4, float invN) {
    int t = blockIdx.x * blockDim.x + threadIdx.x;
    if (t >= n4) return;
    int f0 = (t & 15) * 4;
    float4 v = ((const float4*)io)[t];
    float vv[4] = {v.x, v.y, v.z, v.w};
    float o[4];
#pragma unroll
    for (int j = 0; j < 4; ++j) {
        int f = f0 + j;
        float mean = stats[f] * invN;
        float var = stats[64 + f] * invN - mean * mean;
        float scale = gamma[f] * rsqrtf(var + 1e-5f);
        float shift = beta[f] - mean * scale;
        float y = vv[j] * scale + shift;
        o[j] = y > 0.f ? y : 0.f;
    }
    float4 r = {o[0], o[1], o[2], o[3]};
    ((float4*)io)[t] = r;
}

// ---------------- fallback (push path) kernels ----------------
__global__ __launch_bounds__(THREADS) void deg_kernel(const int* __restrict__ dst, int E,
                                                      int* __restrict__ deg) {
    int e = blockIdx.x * blockDim.x + threadIdx.x;
    if (e < E) atomicAdd(&deg[dst[e]], 1);
}

__global__ __launch_bounds__(THREADS) void dinv_kernel(const int* __restrict__ deg,
                                                       float* __restrict__ dinv, int N) {
    int i = blockIdx.x * blockDim.x + threadIdx.x;
    if (i < N) dinv[i] = rsqrtf((float)deg[i] + 1.0f);
}

__global__ __launch_bounds__(THREADS) void selfloop_kernel(const float4* __restrict__ x4,
                                                           const float* __restrict__ dinv,
                                                           float4* __restrict__ out4, int n4) {
    int t = blockIdx.x * blockDim.x + threadIdx.x;
    if (t >= n4) return;
    int node = t >> 4;
    float s = dinv[node];
    s *= s;
    float4 v = x4[t];
    v.x *= s; v.y *= s; v.z *= s; v.w *= s;
    out4[t] = v;
}

__global__ __launch_bounds__(THREADS) void scatter_kernel(const int* __restrict__ src,
                                                          const int* __restrict__ dst, int E,
                                                          const float* __restrict__ x,
                                                          const float* __restrict__ dinv,
                                                          float* __restrict__ out) {
    int lane = threadIdx.x & 63;
    int wave = (blockIdx.x * blockDim.x + threadIdx.x) >> 6;
    int nwaves = (gridDim.x * blockDim.x) >> 6;
    for (int e = wave; e < E; e += nwaves) {
        int s = src[e];
        int d = dst[e];
        float nrm = dinv[s] * dinv[d];
        atomicAdd(&out[d * 64 + lane], x[s * 64 + lane] * nrm);
    }
}

extern "C" void kernel_launch(void* const* d_in, const int* in_sizes, int n_in,
                              void* d_out, int out_size, void* d_ws, size_t ws_size,
                              hipStream_t stream) {
    const float* x     = (const float*)d_in[0];
    const int*   edges = (const int*)d_in[1];
    const float* W     = (const float*)d_in[2];
    // d_in[3] = b cancels exactly in training-mode BN
    const float* gamma = (const float*)d_in[4];
    const float* beta  = (const float*)d_in[5];
    float* out = (float*)d_out;

    const int N = in_sizes[0] / 64;
    const int E = in_sizes[1] / 2;
    const int* src = edges;
    const int* dst = edges + E;
    const int n4 = N * 16;

    char* ws = (char*)d_ws;
    // layout: stats f32[128] | bcnt[256] | boffs[260] | bcursor[256] |
    //         deg[N] | offs[N] | dinv[N] | csr[E] | staging[E] | xh[64N ushort]
    size_t off_stats   = 0;
    size_t off_bcnt    = 512;
    size_t off_boffs   = off_bcnt + 1024;
    size_t off_bcursor = off_boffs + 1040;
    size_t off_deg     = off_bcursor + 1024;
    size_t off_offs    = off_deg + (size_t)4 * N;
    size_t off_dinv    = off_offs + (size_t)4 * N;
    size_t off_csr     = off_dinv + (size_t)4 * N;
    size_t off_staging = off_csr + (size_t)4 * E;
    size_t off_xh      = (off_staging + (size_t)4 * E + 15) & ~(size_t)15;
    size_t need        = off_xh + (size_t)128 * N;

    if (ws_size >= need && N <= 65536) {
        float* stats   = (float*)(ws + off_stats);
        int*   bcnt    = (int*)(ws + off_bcnt);
        int*   boffs   = (int*)(ws + off_boffs);
        int*   bcursor = (int*)(ws + off_bcursor);
        int*   deg     = (int*)(ws + off_deg);
        int*   offs    = (int*)(ws + off_offs);
        float* dinv    = (float*)(ws + off_dinv);
        int*   csr     = (int*)(ws + off_csr);
        unsigned* staging = (unsigned*)(ws + off_staging);
        ushort* xh     = (ushort*)(ws + off_xh);

        const int nb = (N + 255) >> 8;  // buckets

        init_kernel<<<1, THREADS, 0, stream>>>(bcnt, stats);
        convert_kernel<<<(n4 + THREADS - 1) / THREADS, THREADS, 0, stream>>>(
            (const float4*)x, xh, n4);
        bhist_kernel<<<512, THREADS, 0, stream>>>(dst, E, bcnt);
        bscan_kernel<<<1, THREADS, 0, stream>>>(bcnt, boffs, bcursor);
        int nseg = (E + SEG - 1) / SEG;
        partition_kernel<<<(nseg < 2048 ? nseg : 2048), THREADS, 0, stream>>>(
            src, dst, E, bcursor, staging);
        bucket_build_kernel<<<nb, THREADS, 0, stream>>>(staging, boffs, N, deg, offs, dinv,
                                                        csr);
        gather_bf16_kernel<<<(N * 64 + THREADS - 1) / THREADS, THREADS, 0, stream>>>(
            xh, offs, deg, csr, dinv, out, N);
        int ntiles = (N + 63) >> 6;
        matmul_stats_kernel<<<(ntiles < 1024 ? ntiles : 1024), THREADS, 0, stream>>>(
            out, W, stats, N);
        bn_relu_kernel<<<(n4 + THREADS - 1) / THREADS, THREADS, 0, stream>>>(
            out, stats, gamma, beta, n4, 1.0f / (float)N);
    } else {
        // fallback: push path (ws: deg[N] | stats[128] | dinv[N])
        int*   deg   = (int*)ws;
        float* stats = (float*)(ws + (size_t)N * 4);
        float* dinv  = (float*)(ws + (size_t)N * 4 + 512);

        hipMemsetAsync(ws, 0, (size_t)N * 4 + 512, stream);
        deg_kernel<<<(E + THREADS - 1) / THREADS, THREADS, 0, stream>>>(dst, E, deg);
        dinv_kernel<<<(N + THREADS - 1) / THREADS, THREADS, 0, stream>>>(deg, dinv, N);
        selfloop_kernel<<<(n4 + THREADS - 1) / THREADS, THREADS, 0, stream>>>(
            (const float4*)x, dinv, (float4*)out, n4);
        scatter_kernel<<<1024, THREADS, 0, stream>>>(src, dst, E, x, dinv, out);
        matmul_stats_kernel<<<512, THREADS, 0, stream>>>(out, W, stats, N);
        bn_relu_kernel<<<(n4 + THREADS - 1) / THREADS, THREADS, 0, stream>>>(
            out, stats, gamma, beta, n4, 1.0f / (float)N);
    }
}